// Round 11
// baseline (248.795 us; speedup 1.0000x reference)
//
#include <hip/hip_runtime.h>
#include <hip/hip_fp16.h>

#define HID 128
#define NGRAPH 64
#define CAP 64        // fixed CSR capacity per row (Poisson lambda=12 -> safe)
#define NPB 16        // nodes per block (4 waves x 4 nodes) -> 3125 blocks supply

typedef unsigned int uint32;
typedef unsigned short ushort;
using short8 = __attribute__((ext_vector_type(8))) short;
using f32x4  = __attribute__((ext_vector_type(4))) float;

// fp16 pack/unpack helpers (RNE via v_cvt)
__device__ __forceinline__ float2 h2f2(uint32 u) {
    __half2 h = *(__half2*)&u;
    return __half22float2(h);
}
__device__ __forceinline__ uint32 f2h2(float a, float b) {
    __half2 h;
    h.x = __float2half(a);
    h.y = __float2half(b);
    return *(uint32*)&h;
}

// unpack one fp16x8 row chunk and accumulate into 8 fp32 lane-cols
__device__ __forceinline__ void accum4(float* acc, uint4 v) {
    float2 e0 = h2f2(v.x), e1 = h2f2(v.y), e2 = h2f2(v.z), e3 = h2f2(v.w);
    acc[0] += e0.x; acc[1] += e0.y; acc[2] += e1.x; acc[3] += e1.y;
    acc[4] += e2.x; acc[5] += e2.y; acc[6] += e3.x; acc[7] += e3.y;
}

// shfl 4 edge slots for one node's first round and issue the 4 row-gathers
__device__ __forceinline__ void issue4(const uint32* __restrict__ Sin, int idxv,
                                       int grp, int q, uint4* r) {
    int s1 = __shfl(idxv, grp);
    int s2 = __shfl(idxv, 4 + grp);
    int s3 = __shfl(idxv, 8 + grp);
    int s4 = __shfl(idxv, 12 + grp);
    r[0] = *(const uint4*)(Sin + (size_t)s1 * 64 + q * 4);
    r[1] = *(const uint4*)(Sin + (size_t)s2 * 64 + q * 4);
    r[2] = *(const uint4*)(Sin + (size_t)s3 * 64 + q * 4);
    r[3] = *(const uint4*)(Sin + (size_t)s4 * 64 + q * 4);
}

// ---------------------------------------------------------------------------
// setup: fill=0, zero fp16 pad row (row n) of BOTH gather planes (S1, S2),
// and build gstart[0..NGRAPH] segment-boundary table from sorted batch.
// ---------------------------------------------------------------------------
__global__ void setup(int* __restrict__ fill, uint32* __restrict__ s1,
                      uint32* __restrict__ s2, const int* __restrict__ batch,
                      int* __restrict__ gstart, int n) {
    int i = blockIdx.x * blockDim.x + threadIdx.x;
    if (i < n) fill[i] = 0;
    if (i < 64) {
        s1[(size_t)n * 64 + i] = 0u;     // zero pad row of layer-1 plane
        s2[(size_t)n * 64 + i] = 0u;     // zero pad row of layer-2 plane
    }
    if (i < n) {
        int b0 = batch[i];
        if (i == 0) {
            for (int g = 0; g <= b0; ++g) gstart[g] = 0;   // leading (possibly empty)
        }
        if (i + 1 < n) {
            int b1 = batch[i + 1];
            for (int g = b0 + 1; g <= b1; ++g) gstart[g] = i + 1;
        } else {
            for (int g = b0 + 1; g <= NGRAPH; ++g) gstart[g] = n;  // trailing
        }
    }
}

// ---------------------------------------------------------------------------
// capacity-CSR fill + weight pack fused (single atomic pass, no scan).
// blocks [0,EB): pos = fill[dst]++ ; csr[dst*CAP+pos] = src.
// blocks [EB,EB+128): pack W2,W3 -> transposed single-plane fp16 wt[sel][n][k].
// NOTE: int (not ushort) CSR deliberately — the ushort variant core-dumped
// on HW in a previous round.
// ---------------------------------------------------------------------------
__global__ void csr_fill_pack(const int* __restrict__ src, const int* __restrict__ dst,
                              int* __restrict__ fill, int* __restrict__ csr,
                              int E, int EB,
                              const float* __restrict__ W2, const float* __restrict__ W3,
                              ushort* __restrict__ wt) {
    int b = blockIdx.x;
    if (b < EB) {
        int e = b * blockDim.x + threadIdx.x;
        if (e >= E) return;
        int d = dst[e];
        int pos = atomicAdd(&fill[d], 1);
        if (pos < CAP) csr[(size_t)d * CAP + pos] = src[e];
    } else {
        int t = (b - EB) * blockDim.x + threadIdx.x;   // 0..32767
        int sel = t >> 14;                             // 0: W2, 1: W3
        int idx = t & 16383;
        int nn = idx >> 7, kk = idx & 127;
        const float* W = sel ? W3 : W2;
        wt[sel * 16384 + idx] = __half_as_ushort(__float2half(W[kk * HID + nn]));
    }
}

// ---------------------------------------------------------------------------
// finalize: dis = 1/sqrt(deg) with deg = fill+1 (self-loop); pack
// xp[i] = dis[i] * x[i,:] into 32 B rows (vector-gatherable by layer 1).
// ---------------------------------------------------------------------------
__global__ void finalize(const int* __restrict__ fill, float* __restrict__ dis,
                         const float* __restrict__ x, float4* __restrict__ xp4, int n) {
    int i = blockIdx.x * blockDim.x + threadIdx.x;
    if (i >= n) return;
    int d = fill[i] + 1;
    float di = (float)(1.0 / sqrt((double)d));
    dis[i] = di;
    const float* xi = x + (size_t)i * 6;
    xp4[(size_t)i * 2]     = make_float4(di * xi[0], di * xi[1], di * xi[2], di * xi[3]);
    xp4[(size_t)i * 2 + 1] = make_float4(di * xi[4], di * xi[5], 0.f, 0.f);
}

// ---------------------------------------------------------------------------
// fused layer 1: one wave per node; m <= 64 so each lane gathers its own
// edge's xp row directly, 6 butterfly reductions, then each lane emits
// 2 fp16 output cols.  Stores S1 = dis * relu(xa@W1+b1).
// ---------------------------------------------------------------------------
__global__ __launch_bounds__(256) void layer1_fused(
    const float4* __restrict__ xp4, const int* __restrict__ fill,
    const int* __restrict__ csr, const float* __restrict__ dis,
    const float* __restrict__ W1, const float* __restrict__ b1,
    uint32* __restrict__ S1, int n) {
    int t = blockIdx.x * blockDim.x + threadIdx.x;
    int i = t >> 6, lane = t & 63;
    if (i >= n) return;
    int m = fill[i]; if (m > CAP) m = CAP;
    float a0 = 0.f, a1 = 0.f, a2 = 0.f, a3 = 0.f, a4 = 0.f, a5 = 0.f;
    if (lane < m) {
        int s = csr[(size_t)i * CAP + lane];
        float4 p0 = xp4[(size_t)s * 2];
        float4 p1 = xp4[(size_t)s * 2 + 1];
        a0 = p0.x; a1 = p0.y; a2 = p0.z;
        a3 = p0.w; a4 = p1.x; a5 = p1.y;
    }
#pragma unroll
    for (int off = 32; off > 0; off >>= 1) {
        a0 += __shfl_xor(a0, off); a1 += __shfl_xor(a1, off);
        a2 += __shfl_xor(a2, off); a3 += __shfl_xor(a3, off);
        a4 += __shfl_xor(a4, off); a5 += __shfl_xor(a5, off);
    }
    float di = dis[i];
    float4 s0 = xp4[(size_t)i * 2];
    float4 s1 = xp4[(size_t)i * 2 + 1];
    float xa[6];
    xa[0] = di * (s0.x + a0); xa[1] = di * (s0.y + a1);
    xa[2] = di * (s0.z + a2); xa[3] = di * (s0.w + a3);
    xa[4] = di * (s1.x + a4); xa[5] = di * (s1.y + a5);
    int c0 = lane * 2;
    float z0 = b1[c0], z1 = b1[c0 + 1];
#pragma unroll
    for (int k = 0; k < 6; ++k) {
        z0 += xa[k] * W1[k * HID + c0];
        z1 += xa[k] * W1[k * HID + c0 + 1];
    }
    // scale by dis so the plane is directly gatherable as S = dis*h
    S1[(size_t)i * 64 + lane] = f2h2(di * fmaxf(z0, 0.f), di * fmaxf(z1, 0.f));
}

// ---------------------------------------------------------------------------
// FUSED GCN layer (layers 2 & 3): aggregate-then-GEMM.
//   P_i    = dis_i * (sum_{j in N(i)} Sin_j + Sin_i)     (wave CSR gather)
//   Sout_i = [dis_i *] relu(P_i @ W + b)                 (MFMA, 16x16x32 f16)
//
// R11: 16-deep prefetch PINNED by a memory fence. R8's cross-pair prefetch
// was sunk by the compiler to just-in-time issue (VGPR=60). Here ALL FOUR
// nodes' first-round gathers are issued up front (16 uint4 = 64 VGPR live)
// and `asm volatile("" ::: "memory")` forbids the loads sinking below the
// fence — pair 1's 8 loads stay in flight across pair 0's accumulate
// (compiler emits partial vmcnt waits). Outstanding loads/SIMD:
// R10 6x8=48 -> 5x16=80 (MINW=5) / 4x16=64 (MINW=4).
// A/B: layer 2 <5> (102-VGPR cap) vs layer 3 <4> (128-VGPR cap).
// Mechanism check: VGPR >= 96 on at least one variant, WRITE_SIZE ~12.5 MB
// (no scratch spill — R9's MINW=8 spilled at 77 MB and regressed).
// ---------------------------------------------------------------------------
template<int MINW>
__global__ __launch_bounds__(256, MINW) void layer_agg_gemm(
    const uint32* __restrict__ Sin, const int* __restrict__ fill,
    const int* __restrict__ csr, const float* __restrict__ dis,
    const ushort* __restrict__ WT, const float* __restrict__ bias,
    uint32* __restrict__ Sout, int n, int scaleOut) {
    __shared__ uint4 plds4[NPB * 17];           // 16 rows x 272 B = 4352 B
    const int wave = threadIdx.x >> 6;
    const int lane = threadIdx.x & 63;
    const int grp = lane >> 4;                  // edge-slot group 0..3
    const int q   = lane & 15;                  // uint4 col chunk (8 fp16)
    const int blk0 = blockIdx.x * NPB;
    const int base = blk0 + wave * 4;

    // ---- prologue: prefetch fill + csr index vectors for the 4 nodes ----
    int mt4[4];    // edge count incl. appended self-loop (<= 64)
    int idx4[4];   // this lane's edge slot for node j (pad -> zero row n)
#pragma unroll
    for (int j = 0; j < 4; ++j) {
        int i = base + j;
        int fv = (i < n) ? fill[i] : 0;
        int m = fv > CAP ? CAP : fv;
        idx4[j] = (lane < m) ? csr[(size_t)i * CAP + lane]
                             : ((lane == m && i < n && m < CAP) ? i : n);
        mt4[j] = m + (m < CAP ? 1 : 0);   // append self as slot m
    }

    // ---- phase A: fenced 16-deep gather pipeline, 2 pairs ----
    uint4 pa[4], pb[4], wa[4], wb[4];
    issue4(Sin, idx4[0], grp, q, pa);   // pair 0: 8 uint4
    issue4(Sin, idx4[1], grp, q, pb);
    issue4(Sin, idx4[2], grp, q, wa);   // pair 1: +8 -> 16 in flight
    issue4(Sin, idx4[3], grp, q, wb);
    asm volatile("" ::: "memory");      // loads may NOT sink below this line

    // ---- pair 0 ----
    {
        float acca[8] = {0.f, 0.f, 0.f, 0.f, 0.f, 0.f, 0.f, 0.f};
        float accb[8] = {0.f, 0.f, 0.f, 0.f, 0.f, 0.f, 0.f, 0.f};
        accum4(acca, pa[0]); accum4(acca, pa[1]);
        accum4(acca, pa[2]); accum4(acca, pa[3]);
        accum4(accb, pb[0]); accum4(accb, pb[1]);
        accum4(accb, pb[2]); accum4(accb, pb[3]);
        for (int k = 16; k < mt4[0]; k += 16) {
            int s1 = __shfl(idx4[0], k + grp);
            int s2 = __shfl(idx4[0], k + 4 + grp);
            int s3 = __shfl(idx4[0], k + 8 + grp);
            int s4 = __shfl(idx4[0], k + 12 + grp);
            uint4 v1 = *(const uint4*)(Sin + (size_t)s1 * 64 + q * 4);
            uint4 v2 = *(const uint4*)(Sin + (size_t)s2 * 64 + q * 4);
            uint4 v3 = *(const uint4*)(Sin + (size_t)s3 * 64 + q * 4);
            uint4 v4 = *(const uint4*)(Sin + (size_t)s4 * 64 + q * 4);
            accum4(acca, v1); accum4(acca, v2);
            accum4(acca, v3); accum4(acca, v4);
        }
        for (int k = 16; k < mt4[1]; k += 16) {
            int s1 = __shfl(idx4[1], k + grp);
            int s2 = __shfl(idx4[1], k + 4 + grp);
            int s3 = __shfl(idx4[1], k + 8 + grp);
            int s4 = __shfl(idx4[1], k + 12 + grp);
            uint4 v1 = *(const uint4*)(Sin + (size_t)s1 * 64 + q * 4);
            uint4 v2 = *(const uint4*)(Sin + (size_t)s2 * 64 + q * 4);
            uint4 v3 = *(const uint4*)(Sin + (size_t)s3 * 64 + q * 4);
            uint4 v4 = *(const uint4*)(Sin + (size_t)s4 * 64 + q * 4);
            accum4(accb, v1); accum4(accb, v2);
            accum4(accb, v3); accum4(accb, v4);
        }
#pragma unroll
        for (int r = 0; r < 8; ++r) {
            acca[r] += __shfl_xor(acca[r], 16); acca[r] += __shfl_xor(acca[r], 32);
            accb[r] += __shfl_xor(accb[r], 16); accb[r] += __shfl_xor(accb[r], 32);
        }
        if (grp == 0) {
            int ia = base, ib = base + 1;
            float da = (ia < n) ? dis[ia] : 0.f;
            float db = (ib < n) ? dis[ib] : 0.f;
            plds4[(wave * 4 + 0) * 17 + q] =
                make_uint4(f2h2(da * acca[0], da * acca[1]), f2h2(da * acca[2], da * acca[3]),
                           f2h2(da * acca[4], da * acca[5]), f2h2(da * acca[6], da * acca[7]));
            plds4[(wave * 4 + 1) * 17 + q] =
                make_uint4(f2h2(db * accb[0], db * accb[1]), f2h2(db * accb[2], db * accb[3]),
                           f2h2(db * accb[4], db * accb[5]), f2h2(db * accb[6], db * accb[7]));
        }
    }
    // ---- pair 1 (loads wa/wb were in flight through pair 0's work) ----
    {
        float acca[8] = {0.f, 0.f, 0.f, 0.f, 0.f, 0.f, 0.f, 0.f};
        float accb[8] = {0.f, 0.f, 0.f, 0.f, 0.f, 0.f, 0.f, 0.f};
        accum4(acca, wa[0]); accum4(acca, wa[1]);
        accum4(acca, wa[2]); accum4(acca, wa[3]);
        accum4(accb, wb[0]); accum4(accb, wb[1]);
        accum4(accb, wb[2]); accum4(accb, wb[3]);
        for (int k = 16; k < mt4[2]; k += 16) {
            int s1 = __shfl(idx4[2], k + grp);
            int s2 = __shfl(idx4[2], k + 4 + grp);
            int s3 = __shfl(idx4[2], k + 8 + grp);
            int s4 = __shfl(idx4[2], k + 12 + grp);
            uint4 v1 = *(const uint4*)(Sin + (size_t)s1 * 64 + q * 4);
            uint4 v2 = *(const uint4*)(Sin + (size_t)s2 * 64 + q * 4);
            uint4 v3 = *(const uint4*)(Sin + (size_t)s3 * 64 + q * 4);
            uint4 v4 = *(const uint4*)(Sin + (size_t)s4 * 64 + q * 4);
            accum4(acca, v1); accum4(acca, v2);
            accum4(acca, v3); accum4(acca, v4);
        }
        for (int k = 16; k < mt4[3]; k += 16) {
            int s1 = __shfl(idx4[3], k + grp);
            int s2 = __shfl(idx4[3], k + 4 + grp);
            int s3 = __shfl(idx4[3], k + 8 + grp);
            int s4 = __shfl(idx4[3], k + 12 + grp);
            uint4 v1 = *(const uint4*)(Sin + (size_t)s1 * 64 + q * 4);
            uint4 v2 = *(const uint4*)(Sin + (size_t)s2 * 64 + q * 4);
            uint4 v3 = *(const uint4*)(Sin + (size_t)s3 * 64 + q * 4);
            uint4 v4 = *(const uint4*)(Sin + (size_t)s4 * 64 + q * 4);
            accum4(accb, v1); accum4(accb, v2);
            accum4(accb, v3); accum4(accb, v4);
        }
#pragma unroll
        for (int r = 0; r < 8; ++r) {
            acca[r] += __shfl_xor(acca[r], 16); acca[r] += __shfl_xor(acca[r], 32);
            accb[r] += __shfl_xor(accb[r], 16); accb[r] += __shfl_xor(accb[r], 32);
        }
        if (grp == 0) {
            int ia = base + 2, ib = base + 3;
            float da = (ia < n) ? dis[ia] : 0.f;
            float db = (ib < n) ? dis[ib] : 0.f;
            plds4[(wave * 4 + 2) * 17 + q] =
                make_uint4(f2h2(da * acca[0], da * acca[1]), f2h2(da * acca[2], da * acca[3]),
                           f2h2(da * acca[4], da * acca[5]), f2h2(da * acca[6], da * acca[7]));
            plds4[(wave * 4 + 3) * 17 + q] =
                make_uint4(f2h2(db * accb[0], db * accb[1]), f2h2(db * accb[2], db * accb[3]),
                           f2h2(db * accb[4], db * accb[5]), f2h2(db * accb[6], db * accb[7]));
        }
    }
    __syncthreads();

    // ---- phase B: 16x128 GEMM out = [dis*] relu(P @ W + b) ----
    // wave w owns cols [w*32, w*32+32); 16 rows; 8 MFMA per wave.
    const int l16 = lane & 15, quad = lane >> 4;
    f32x4 acc2[2] = {};
#pragma unroll
    for (int kc = 0; kc < 4; ++kc) {
        int ko = kc * 32 + quad * 8;
        short8 a0 = *(const short8*)&plds4[(size_t)l16 * 17 + kc * 4 + quad];
#pragma unroll
        for (int ct = 0; ct < 2; ++ct) {
            short8 wh = *(const short8*)(WT + (size_t)(wave * 32 + ct * 16 + l16) * HID + ko);
            acc2[ct] = __builtin_amdgcn_mfma_f32_16x16x32_f16(wh, a0, acc2[ct], 0, 0, 0);
        }
    }
    ushort* so = (ushort*)Sout;
    int node = blk0 + l16;
    if (node < n) {
        float sc = scaleOut ? dis[node] : 1.f;
#pragma unroll
        for (int ct = 0; ct < 2; ++ct) {
            int cb = wave * 32 + ct * 16 + quad * 4;
            float4 bv = *(const float4*)(bias + cb);
            float o0 = fmaxf(acc2[ct][0] + bv.x, 0.f) * sc;
            float o1 = fmaxf(acc2[ct][1] + bv.y, 0.f) * sc;
            float o2 = fmaxf(acc2[ct][2] + bv.z, 0.f) * sc;
            float o3 = fmaxf(acc2[ct][3] + bv.w, 0.f) * sc;
            *(uint2*)(so + (size_t)node * HID + cb) = make_uint2(f2h2(o0, o1), f2h2(o2, o3));
        }
    }
}

// ---------------------------------------------------------------------------
// FUSED pool + head: one block per graph; segment bounds from precomputed
// gstart table. 4 waves stream rows, LDS reduce, wave 0 runs the MLP head.
// ---------------------------------------------------------------------------
__global__ __launch_bounds__(256) void pool_head(
    const uint32* __restrict__ h, const int* __restrict__ gstart,
    const float* __restrict__ fc1w, const float* __restrict__ fc1b,
    const float* __restrict__ fc2w, const float* __restrict__ fc2b,
    float* __restrict__ out, int n) {
    __shared__ float red[4][128];
    __shared__ float pp[128];
    const int g = blockIdx.x;
    const int t = threadIdx.x;
    const int sub = t >> 6, c = t & 63;

    const int start = gstart[g], end = gstart[g + 1];

    float sx = 0.f, sy = 0.f;
    int i = start + sub;
    for (; i + 12 < end; i += 16) {       // 4 rows x unroll 4 in flight
        uint32 u0 = h[(size_t)i * 64 + c];
        uint32 u1 = h[(size_t)(i + 4) * 64 + c];
        uint32 u2 = h[(size_t)(i + 8) * 64 + c];
        uint32 u3 = h[(size_t)(i + 12) * 64 + c];
        float2 v0 = h2f2(u0), v1 = h2f2(u1), v2 = h2f2(u2), v3 = h2f2(u3);
        sx += v0.x + v1.x + v2.x + v3.x;
        sy += v0.y + v1.y + v2.y + v3.y;
    }
    for (; i < end; i += 4) {
        float2 v = h2f2(h[(size_t)i * 64 + c]);
        sx += v.x; sy += v.y;
    }
    *(float2*)&red[sub][2 * c] = make_float2(sx, sy);
    __syncthreads();

    if (t < 64) {
        float2 r0 = *(float2*)&red[0][2 * t];
        float2 r1 = *(float2*)&red[1][2 * t];
        float2 r2 = *(float2*)&red[2][2 * t];
        float2 r3 = *(float2*)&red[3][2 * t];
        float inv = 1.0f / fmaxf((float)(end - start), 1.0f);
        pp[2 * t]     = (r0.x + r1.x + r2.x + r3.x) * inv;
        pp[2 * t + 1] = (r0.y + r1.y + r2.y + r3.y) * inv;
        // same wave writes then reads pp: lgkmcnt ordering suffices
        float z = fc1b[t];
#pragma unroll 8
        for (int k = 0; k < HID; ++k) z += pp[k] * fc1w[k * 64 + t];
        z = fmaxf(z, 0.f);
        float v = z * fc2w[t];
#pragma unroll
        for (int off = 32; off > 0; off >>= 1) v += __shfl_down(v, off);
        if (t == 0) out[g] = v + fc2b[0];
    }
}

// ---------------------------------------------------------------------------
extern "C" void kernel_launch(void* const* d_in, const int* in_sizes, int n_in,
                              void* d_out, int out_size, void* d_ws, size_t ws_size,
                              hipStream_t stream) {
    const float* x     = (const float*)d_in[0];
    const int*   ei    = (const int*)d_in[1];
    const int*   batch = (const int*)d_in[2];
    const float* W1    = (const float*)d_in[3];
    const float* b1    = (const float*)d_in[4];
    const float* W2    = (const float*)d_in[5];
    const float* b2    = (const float*)d_in[6];
    const float* W3    = (const float*)d_in[7];
    const float* b3    = (const float*)d_in[8];
    const float* fc1w  = (const float*)d_in[9];
    const float* fc1b  = (const float*)d_in[10];
    const float* fc2w  = (const float*)d_in[11];
    const float* fc2b  = (const float*)d_in[12];
    float* out = (float*)d_out;

    const int N = in_sizes[0] / 6;   // 50000
    const int E = in_sizes[1] / 2;   // 600000
    const int* src = ei;
    const int* dst = ei + E;

    char* ws = (char*)d_ws;
    char* p = ws;
    uint32* S1   = (uint32*)p;   p += (size_t)(N + 1) * 256;      // dis*h1 fp16 plane (+pad row)
    uint32* S2   = (uint32*)p;   p += (size_t)(N + 1) * 256;      // dis*h2 fp16 plane (+pad row)
    uint32* B1h  = (uint32*)p;   p += (size_t)N * 256;            // fp16 final acts (h3)
    float4* xp4  = (float4*)p;   p += (size_t)N * 32;             // dis-scaled x rows
    ushort* WT   = (ushort*)p;   p += 2 * 32768;                  // packed W2,W3 (fp16)
    float* dis     = (float*)p;  p += (size_t)N * 4;
    int*   fill    = (int*)p;    p += (size_t)N * 4;
    int*   csr     = (int*)p;    p += (size_t)N * CAP * 4;        // capacity CSR
    int*   gstart  = (int*)p;    p += (NGRAPH + 1) * 4;           // pool segment bounds

    const int B = 256;
    const int EB = (E + B - 1) / B;

    // ---- setup + capacity-CSR build (no count pass, no scan) ----
    setup<<<(N + B - 1) / B, B, 0, stream>>>(fill, S1, S2, batch, gstart, N);
    csr_fill_pack<<<EB + 128, B, 0, stream>>>(src, dst, fill, csr, E, EB, W2, W3, WT);
    finalize<<<(N + B - 1) / B, B, 0, stream>>>(fill, dis, x, xp4, N);

    int nodeWaveBlocks = (int)(((size_t)N * 64 + B - 1) / B);
    int fusedBlocks = (N + NPB - 1) / NPB;

    // ---- layer 1 (fused aggregate + GEMM + bias + relu + dis-scale) ----
    layer1_fused<<<nodeWaveBlocks, B, 0, stream>>>(xp4, fill, csr, dis, W1, b1, S1, N);

    // ---- layer 2: fused (A*S1) then @W2 (+b2, relu, *dis) -> S2.  MINW=5 (A) ----
    layer_agg_gemm<5><<<fusedBlocks, B, 0, stream>>>(S1, fill, csr, dis, WT, b2, S2, N, 1);

    // ---- layer 3: fused (A*S2) then @W3 (+b3, relu) -> B1h.  MINW=4 (B) ----
    layer_agg_gemm<4><<<fusedBlocks, B, 0, stream>>>(S2, fill, csr, dis, WT + 16384, b3, B1h, N, 0);

    // ---- fused pool + head (one block per graph, no atomics, no search) ----
    pool_head<<<NGRAPH, B, 0, stream>>>(B1h, gstart, fc1w, fc1b, fc2w, fc2b, out, N);
}

// Round 12
// 221.399 us; speedup vs baseline: 1.1237x; 1.1237x over previous
//
#include <hip/hip_runtime.h>
#include <hip/hip_fp16.h>

#define HID 128
#define NGRAPH 64
#define CAP 64        // fixed CSR capacity per row (Poisson lambda=12 -> safe)
#define NPB 16        // nodes per block (4 waves x 4 nodes) in fused layers

typedef unsigned int uint32;
typedef unsigned short ushort;
using short8 = __attribute__((ext_vector_type(8))) short;
using f32x4  = __attribute__((ext_vector_type(4))) float;

// fp16 pack/unpack helpers (RNE via v_cvt)
__device__ __forceinline__ float2 h2f2(uint32 u) {
    __half2 h = *(__half2*)&u;
    return __half22float2(h);
}
__device__ __forceinline__ uint32 f2h2(float a, float b) {
    __half2 h;
    h.x = __float2half(a);
    h.y = __float2half(b);
    return *(uint32*)&h;
}

// unpack one fp16x8 row chunk and accumulate into 8 fp32 lane-cols
__device__ __forceinline__ void accum4(float* acc, uint4 v) {
    float2 e0 = h2f2(v.x), e1 = h2f2(v.y), e2 = h2f2(v.z), e3 = h2f2(v.w);
    acc[0] += e0.x; acc[1] += e0.y; acc[2] += e1.x; acc[3] += e1.y;
    acc[4] += e2.x; acc[5] += e2.y; acc[6] += e3.x; acc[7] += e3.y;
}

// ---------------------------------------------------------------------------
// setup: fill=0, zero fp16 pad row (row n) of BOTH gather planes (S1, S2),
// and build gstart[0..NGRAPH] segment-boundary table from sorted batch.
// ---------------------------------------------------------------------------
__global__ void setup(int* __restrict__ fill, uint32* __restrict__ s1,
                      uint32* __restrict__ s2, const int* __restrict__ batch,
                      int* __restrict__ gstart, int n) {
    int i = blockIdx.x * blockDim.x + threadIdx.x;
    if (i < n) fill[i] = 0;
    if (i < 64) {
        s1[(size_t)n * 64 + i] = 0u;     // zero pad row of layer-1 plane
        s2[(size_t)n * 64 + i] = 0u;     // zero pad row of layer-2 plane
    }
    if (i < n) {
        int b0 = batch[i];
        if (i == 0) {
            for (int g = 0; g <= b0; ++g) gstart[g] = 0;   // leading (possibly empty)
        }
        if (i + 1 < n) {
            int b1 = batch[i + 1];
            for (int g = b0 + 1; g <= b1; ++g) gstart[g] = i + 1;
        } else {
            for (int g = b0 + 1; g <= NGRAPH; ++g) gstart[g] = n;  // trailing
        }
    }
}

// ---------------------------------------------------------------------------
// capacity-CSR fill + weight pack fused (single atomic pass, no scan).
// blocks [0,EB): pos = fill[dst]++ ; csr[dst*CAP+pos] = src.
// blocks [EB,EB+128): pack W2,W3 -> transposed single-plane fp16 wt[sel][n][k].
// NOTE: int (not ushort) CSR deliberately — the ushort variant core-dumped
// on HW in a previous round.
// ---------------------------------------------------------------------------
__global__ void csr_fill_pack(const int* __restrict__ src, const int* __restrict__ dst,
                              int* __restrict__ fill, int* __restrict__ csr,
                              int E, int EB,
                              const float* __restrict__ W2, const float* __restrict__ W3,
                              ushort* __restrict__ wt) {
    int b = blockIdx.x;
    if (b < EB) {
        int e = b * blockDim.x + threadIdx.x;
        if (e >= E) return;
        int d = dst[e];
        int pos = atomicAdd(&fill[d], 1);
        if (pos < CAP) csr[(size_t)d * CAP + pos] = src[e];
    } else {
        int t = (b - EB) * blockDim.x + threadIdx.x;   // 0..32767
        int sel = t >> 14;                             // 0: W2, 1: W3
        int idx = t & 16383;
        int nn = idx >> 7, kk = idx & 127;
        const float* W = sel ? W3 : W2;
        wt[sel * 16384 + idx] = __half_as_ushort(__float2half(W[kk * HID + nn]));
    }
}

// ---------------------------------------------------------------------------
// finalize: dis = 1/sqrt(deg) with deg = fill+1 (self-loop); pack
// xp[i] = dis[i] * x[i,:] into 32 B rows (vector-gatherable by layer 1).
// ---------------------------------------------------------------------------
__global__ void finalize(const int* __restrict__ fill, float* __restrict__ dis,
                         const float* __restrict__ x, float4* __restrict__ xp4, int n) {
    int i = blockIdx.x * blockDim.x + threadIdx.x;
    if (i >= n) return;
    int d = fill[i] + 1;
    float di = (float)(1.0 / sqrt((double)d));
    dis[i] = di;
    const float* xi = x + (size_t)i * 6;
    xp4[(size_t)i * 2]     = make_float4(di * xi[0], di * xi[1], di * xi[2], di * xi[3]);
    xp4[(size_t)i * 2 + 1] = make_float4(di * xi[4], di * xi[5], 0.f, 0.f);
}

// ---------------------------------------------------------------------------
// layer 1, R12 redesign: FOUR nodes per wave (16-lane group per node).
// Mean degree 12 means the old one-wave-per-node form left ~52/64 lanes
// idle in the gather and ran a 6-step/64-lane butterfly. Here lane sl of
// node-group handles edge slots sl, sl+16, sl+32, sl+48 (>=89% of nodes
// finish in round 0), self-loop folded in directly, reduce = 4 butterfly
// steps over 16 lanes, each lane emits 8 cols of S1 = dis*relu(xa@W1+b1)
// as one uint4 store.
// ---------------------------------------------------------------------------
__global__ __launch_bounds__(256) void layer1_quad(
    const float4* __restrict__ xp4, const int* __restrict__ fill,
    const int* __restrict__ csr, const float* __restrict__ dis,
    const float* __restrict__ W1, const float* __restrict__ b1,
    uint32* __restrict__ S1, int n) {
    int t = blockIdx.x * blockDim.x + threadIdx.x;
    int wv = t >> 6;                 // wave id
    int lane = t & 63;
    int sub = lane >> 4;             // node slot within wave (0..3)
    int sl  = lane & 15;             // lane slot within node
    int i = wv * 4 + sub;
    if (i >= n) return;              // whole 16-lane group exits together

    int m = fill[i]; if (m > CAP) m = CAP;
    float a0 = 0.f, a1 = 0.f, a2 = 0.f, a3 = 0.f, a4 = 0.f, a5 = 0.f;
#pragma unroll
    for (int r = 0; r < 4; ++r) {
        int slot = sl + 16 * r;
        if (slot < m) {
            int s = csr[(size_t)i * CAP + slot];
            float4 p0 = xp4[(size_t)s * 2];
            float4 p1 = xp4[(size_t)s * 2 + 1];
            a0 += p0.x; a1 += p0.y; a2 += p0.z;
            a3 += p0.w; a4 += p1.x; a5 += p1.y;
        }
    }
    // butterfly reduce within the 16-lane group (offsets stay in-group)
#pragma unroll
    for (int off = 8; off > 0; off >>= 1) {
        a0 += __shfl_xor(a0, off); a1 += __shfl_xor(a1, off);
        a2 += __shfl_xor(a2, off); a3 += __shfl_xor(a3, off);
        a4 += __shfl_xor(a4, off); a5 += __shfl_xor(a5, off);
    }
    float di = dis[i];
    float4 s0 = xp4[(size_t)i * 2];
    float4 s1v = xp4[(size_t)i * 2 + 1];
    float xa[6];
    xa[0] = di * (s0.x + a0); xa[1] = di * (s0.y + a1);
    xa[2] = di * (s0.z + a2); xa[3] = di * (s0.w + a3);
    xa[4] = di * (s1v.x + a4); xa[5] = di * (s1v.y + a5);

    int c0 = sl * 8;                 // this lane's 8 output cols
    float z[8];
#pragma unroll
    for (int j = 0; j < 8; ++j) z[j] = b1[c0 + j];
#pragma unroll
    for (int k = 0; k < 6; ++k) {
#pragma unroll
        for (int j = 0; j < 8; ++j) z[j] += xa[k] * W1[k * HID + c0 + j];
    }
    uint4 h4 = make_uint4(f2h2(di * fmaxf(z[0], 0.f), di * fmaxf(z[1], 0.f)),
                          f2h2(di * fmaxf(z[2], 0.f), di * fmaxf(z[3], 0.f)),
                          f2h2(di * fmaxf(z[4], 0.f), di * fmaxf(z[5], 0.f)),
                          f2h2(di * fmaxf(z[6], 0.f), di * fmaxf(z[7], 0.f)));
    *(uint4*)(S1 + (size_t)i * 64 + sl * 4) = h4;
}

// ---------------------------------------------------------------------------
// FUSED GCN layer (layers 2 & 3): aggregate-then-GEMM.  R10-PROVEN CONFIG
// (best verified: 231.5 us total). 16 nodes/block, 4/wave, simple 2-pair
// body with 8 uint4 in flight. ILP-deepening past 8 is source-unreachable:
// R8 sink (VGPR 60), R9 spill (MINW=8 -> VGPR 32 + 77MB scratch), R11
// fence -> partial spill (VGPR 48 + 38MB scratch). Do not revisit.
// ---------------------------------------------------------------------------
template<int MINW>
__global__ __launch_bounds__(256, MINW) void layer_agg_gemm(
    const uint32* __restrict__ Sin, const int* __restrict__ fill,
    const int* __restrict__ csr, const float* __restrict__ dis,
    const ushort* __restrict__ WT, const float* __restrict__ bias,
    uint32* __restrict__ Sout, int n, int scaleOut) {
    __shared__ uint4 plds4[NPB * 17];           // 16 rows x 272 B = 4352 B
    const int wave = threadIdx.x >> 6;
    const int lane = threadIdx.x & 63;
    const int grp = lane >> 4;                  // edge-slot group 0..3
    const int q   = lane & 15;                  // uint4 col chunk (8 fp16)
    const int blk0 = blockIdx.x * NPB;
    const int base = blk0 + wave * 4;

    // ---- prologue: prefetch fill + csr index vectors for the 4 nodes ----
    int mt4[4];    // edge count incl. appended self-loop (<= 64)
    int idx4[4];   // this lane's edge slot for node j (pad -> zero row n)
#pragma unroll
    for (int j = 0; j < 4; ++j) {
        int i = base + j;
        int fv = (i < n) ? fill[i] : 0;
        int m = fv > CAP ? CAP : fv;
        idx4[j] = (lane < m) ? csr[(size_t)i * CAP + lane]
                             : ((lane == m && i < n && m < CAP) ? i : n);
        mt4[j] = m + (m < CAP ? 1 : 0);   // append self as slot m
    }

    // ---- phase A: paired gather-aggregate into LDS (2 pairs) ----
#pragma unroll
    for (int jp = 0; jp < 2; ++jp) {
        const int ja = jp * 2, jb = ja + 1;
        float acca[8] = {0.f, 0.f, 0.f, 0.f, 0.f, 0.f, 0.f, 0.f};
        float accb[8] = {0.f, 0.f, 0.f, 0.f, 0.f, 0.f, 0.f, 0.f};
        // first 16-edge round of BOTH nodes co-issued (8 uint4 in flight)
        {
            int sa1 = __shfl(idx4[ja], grp);
            int sa2 = __shfl(idx4[ja], 4 + grp);
            int sa3 = __shfl(idx4[ja], 8 + grp);
            int sa4 = __shfl(idx4[ja], 12 + grp);
            int sb1 = __shfl(idx4[jb], grp);
            int sb2 = __shfl(idx4[jb], 4 + grp);
            int sb3 = __shfl(idx4[jb], 8 + grp);
            int sb4 = __shfl(idx4[jb], 12 + grp);
            uint4 va1 = *(const uint4*)(Sin + (size_t)sa1 * 64 + q * 4);
            uint4 va2 = *(const uint4*)(Sin + (size_t)sa2 * 64 + q * 4);
            uint4 va3 = *(const uint4*)(Sin + (size_t)sa3 * 64 + q * 4);
            uint4 va4 = *(const uint4*)(Sin + (size_t)sa4 * 64 + q * 4);
            uint4 vb1 = *(const uint4*)(Sin + (size_t)sb1 * 64 + q * 4);
            uint4 vb2 = *(const uint4*)(Sin + (size_t)sb2 * 64 + q * 4);
            uint4 vb3 = *(const uint4*)(Sin + (size_t)sb3 * 64 + q * 4);
            uint4 vb4 = *(const uint4*)(Sin + (size_t)sb4 * 64 + q * 4);
            accum4(acca, va1); accum4(acca, va2);
            accum4(acca, va3); accum4(acca, va4);
            accum4(accb, vb1); accum4(accb, vb2);
            accum4(accb, vb3); accum4(accb, vb4);
        }
        // remainder rounds (m >= 16), serial per node
        for (int k = 16; k < mt4[ja]; k += 16) {
            int s1 = __shfl(idx4[ja], k + grp);
            int s2 = __shfl(idx4[ja], k + 4 + grp);
            int s3 = __shfl(idx4[ja], k + 8 + grp);
            int s4 = __shfl(idx4[ja], k + 12 + grp);
            uint4 v1 = *(const uint4*)(Sin + (size_t)s1 * 64 + q * 4);
            uint4 v2 = *(const uint4*)(Sin + (size_t)s2 * 64 + q * 4);
            uint4 v3 = *(const uint4*)(Sin + (size_t)s3 * 64 + q * 4);
            uint4 v4 = *(const uint4*)(Sin + (size_t)s4 * 64 + q * 4);
            accum4(acca, v1); accum4(acca, v2);
            accum4(acca, v3); accum4(acca, v4);
        }
        for (int k = 16; k < mt4[jb]; k += 16) {
            int s1 = __shfl(idx4[jb], k + grp);
            int s2 = __shfl(idx4[jb], k + 4 + grp);
            int s3 = __shfl(idx4[jb], k + 8 + grp);
            int s4 = __shfl(idx4[jb], k + 12 + grp);
            uint4 v1 = *(const uint4*)(Sin + (size_t)s1 * 64 + q * 4);
            uint4 v2 = *(const uint4*)(Sin + (size_t)s2 * 64 + q * 4);
            uint4 v3 = *(const uint4*)(Sin + (size_t)s3 * 64 + q * 4);
            uint4 v4 = *(const uint4*)(Sin + (size_t)s4 * 64 + q * 4);
            accum4(accb, v1); accum4(accb, v2);
            accum4(accb, v3); accum4(accb, v4);
        }
        // cross-group butterfly reduce (4 groups -> full row sums)
#pragma unroll
        for (int r = 0; r < 8; ++r) {
            acca[r] += __shfl_xor(acca[r], 16);
            acca[r] += __shfl_xor(acca[r], 32);
            accb[r] += __shfl_xor(accb[r], 16);
            accb[r] += __shfl_xor(accb[r], 32);
        }
        if (grp == 0) {
            int ia = base + ja, ib = base + jb;
            float da = (ia < n) ? dis[ia] : 0.f;
            float db = (ib < n) ? dis[ib] : 0.f;
            plds4[(wave * 4 + ja) * 17 + q] =
                make_uint4(f2h2(da * acca[0], da * acca[1]),
                           f2h2(da * acca[2], da * acca[3]),
                           f2h2(da * acca[4], da * acca[5]),
                           f2h2(da * acca[6], da * acca[7]));
            plds4[(wave * 4 + jb) * 17 + q] =
                make_uint4(f2h2(db * accb[0], db * accb[1]),
                           f2h2(db * accb[2], db * accb[3]),
                           f2h2(db * accb[4], db * accb[5]),
                           f2h2(db * accb[6], db * accb[7]));
        }
    }
    __syncthreads();

    // ---- phase B: 16x128 GEMM out = [dis*] relu(P @ W + b) ----
    // wave w owns cols [w*32, w*32+32); 16 rows; 8 MFMA per wave.
    const int l16 = lane & 15, quad = lane >> 4;
    f32x4 acc2[2] = {};
#pragma unroll
    for (int kc = 0; kc < 4; ++kc) {
        int ko = kc * 32 + quad * 8;
        short8 a0 = *(const short8*)&plds4[(size_t)l16 * 17 + kc * 4 + quad];
#pragma unroll
        for (int ct = 0; ct < 2; ++ct) {
            short8 wh = *(const short8*)(WT + (size_t)(wave * 32 + ct * 16 + l16) * HID + ko);
            acc2[ct] = __builtin_amdgcn_mfma_f32_16x16x32_f16(wh, a0, acc2[ct], 0, 0, 0);
        }
    }
    ushort* so = (ushort*)Sout;
    int node = blk0 + l16;
    if (node < n) {
        float sc = scaleOut ? dis[node] : 1.f;
#pragma unroll
        for (int ct = 0; ct < 2; ++ct) {
            int cb = wave * 32 + ct * 16 + quad * 4;
            float4 bv = *(const float4*)(bias + cb);
            float o0 = fmaxf(acc2[ct][0] + bv.x, 0.f) * sc;
            float o1 = fmaxf(acc2[ct][1] + bv.y, 0.f) * sc;
            float o2 = fmaxf(acc2[ct][2] + bv.z, 0.f) * sc;
            float o3 = fmaxf(acc2[ct][3] + bv.w, 0.f) * sc;
            *(uint2*)(so + (size_t)node * HID + cb) = make_uint2(f2h2(o0, o1), f2h2(o2, o3));
        }
    }
}

// ---------------------------------------------------------------------------
// FUSED pool + head: one block per graph; segment bounds from precomputed
// gstart table. 4 waves stream rows, LDS reduce, wave 0 runs the MLP head.
// ---------------------------------------------------------------------------
__global__ __launch_bounds__(256) void pool_head(
    const uint32* __restrict__ h, const int* __restrict__ gstart,
    const float* __restrict__ fc1w, const float* __restrict__ fc1b,
    const float* __restrict__ fc2w, const float* __restrict__ fc2b,
    float* __restrict__ out, int n) {
    __shared__ float red[4][128];
    __shared__ float pp[128];
    const int g = blockIdx.x;
    const int t = threadIdx.x;
    const int sub = t >> 6, c = t & 63;

    const int start = gstart[g], end = gstart[g + 1];

    float sx = 0.f, sy = 0.f;
    int i = start + sub;
    for (; i + 12 < end; i += 16) {       // 4 rows x unroll 4 in flight
        uint32 u0 = h[(size_t)i * 64 + c];
        uint32 u1 = h[(size_t)(i + 4) * 64 + c];
        uint32 u2 = h[(size_t)(i + 8) * 64 + c];
        uint32 u3 = h[(size_t)(i + 12) * 64 + c];
        float2 v0 = h2f2(u0), v1 = h2f2(u1), v2 = h2f2(u2), v3 = h2f2(u3);
        sx += v0.x + v1.x + v2.x + v3.x;
        sy += v0.y + v1.y + v2.y + v3.y;
    }
    for (; i < end; i += 4) {
        float2 v = h2f2(h[(size_t)i * 64 + c]);
        sx += v.x; sy += v.y;
    }
    *(float2*)&red[sub][2 * c] = make_float2(sx, sy);
    __syncthreads();

    if (t < 64) {
        float2 r0 = *(float2*)&red[0][2 * t];
        float2 r1 = *(float2*)&red[1][2 * t];
        float2 r2 = *(float2*)&red[2][2 * t];
        float2 r3 = *(float2*)&red[3][2 * t];
        float inv = 1.0f / fmaxf((float)(end - start), 1.0f);
        pp[2 * t]     = (r0.x + r1.x + r2.x + r3.x) * inv;
        pp[2 * t + 1] = (r0.y + r1.y + r2.y + r3.y) * inv;
        // same wave writes then reads pp: lgkmcnt ordering suffices
        float z = fc1b[t];
#pragma unroll 8
        for (int k = 0; k < HID; ++k) z += pp[k] * fc1w[k * 64 + t];
        z = fmaxf(z, 0.f);
        float v = z * fc2w[t];
#pragma unroll
        for (int off = 32; off > 0; off >>= 1) v += __shfl_down(v, off);
        if (t == 0) out[g] = v + fc2b[0];
    }
}

// ---------------------------------------------------------------------------
extern "C" void kernel_launch(void* const* d_in, const int* in_sizes, int n_in,
                              void* d_out, int out_size, void* d_ws, size_t ws_size,
                              hipStream_t stream) {
    const float* x     = (const float*)d_in[0];
    const int*   ei    = (const int*)d_in[1];
    const int*   batch = (const int*)d_in[2];
    const float* W1    = (const float*)d_in[3];
    const float* b1    = (const float*)d_in[4];
    const float* W2    = (const float*)d_in[5];
    const float* b2    = (const float*)d_in[6];
    const float* W3    = (const float*)d_in[7];
    const float* b3    = (const float*)d_in[8];
    const float* fc1w  = (const float*)d_in[9];
    const float* fc1b  = (const float*)d_in[10];
    const float* fc2w  = (const float*)d_in[11];
    const float* fc2b  = (const float*)d_in[12];
    float* out = (float*)d_out;

    const int N = in_sizes[0] / 6;   // 50000
    const int E = in_sizes[1] / 2;   // 600000
    const int* src = ei;
    const int* dst = ei + E;

    char* ws = (char*)d_ws;
    char* p = ws;
    uint32* S1   = (uint32*)p;   p += (size_t)(N + 1) * 256;      // dis*h1 fp16 plane (+pad row)
    uint32* S2   = (uint32*)p;   p += (size_t)(N + 1) * 256;      // dis*h2 fp16 plane (+pad row)
    uint32* B1h  = (uint32*)p;   p += (size_t)N * 256;            // fp16 final acts (h3)
    float4* xp4  = (float4*)p;   p += (size_t)N * 32;             // dis-scaled x rows
    ushort* WT   = (ushort*)p;   p += 2 * 32768;                  // packed W2,W3 (fp16)
    float* dis     = (float*)p;  p += (size_t)N * 4;
    int*   fill    = (int*)p;    p += (size_t)N * 4;
    int*   csr     = (int*)p;    p += (size_t)N * CAP * 4;        // capacity CSR
    int*   gstart  = (int*)p;    p += (NGRAPH + 1) * 4;           // pool segment bounds

    const int B = 256;
    const int EB = (E + B - 1) / B;

    // ---- setup + capacity-CSR build (no count pass, no scan) ----
    setup<<<(N + B - 1) / B, B, 0, stream>>>(fill, S1, S2, batch, gstart, N);
    csr_fill_pack<<<EB + 128, B, 0, stream>>>(src, dst, fill, csr, E, EB, W2, W3, WT);
    finalize<<<(N + B - 1) / B, B, 0, stream>>>(fill, dis, x, xp4, N);

    int l1Blocks = (int)(((size_t)N * 16 + B - 1) / B);    // 4 nodes/wave
    int fusedBlocks = (N + NPB - 1) / NPB;

    // ---- layer 1 (4 nodes/wave, fused aggregate + GEMV + relu + dis-scale) ----
    layer1_quad<<<l1Blocks, B, 0, stream>>>(xp4, fill, csr, dis, W1, b1, S1, N);

    // ---- layer 2: fused (A*S1) then @W2 (+b2, relu, *dis) -> S2 ----
    layer_agg_gemm<6><<<fusedBlocks, B, 0, stream>>>(S1, fill, csr, dis, WT, b2, S2, N, 1);

    // ---- layer 3: fused (A*S2) then @W3 (+b3, relu) -> B1h (unscaled) ----
    layer_agg_gemm<5><<<fusedBlocks, B, 0, stream>>>(S2, fill, csr, dis, WT + 16384, b3, B1h, N, 0);

    // ---- fused pool + head (one block per graph, no atomics, no search) ----
    pool_head<<<NGRAPH, B, 0, stream>>>(B1h, gstart, fc1w, fc1b, fc2w, fc2b, out, N);
}

// Round 13
// 219.065 us; speedup vs baseline: 1.1357x; 1.0107x over previous
//
#include <hip/hip_runtime.h>
#include <hip/hip_fp16.h>

#define HID 128
#define NGRAPH 64
#define CAP 64        // fixed CSR capacity per row (Poisson lambda=12 -> safe)
#define NPB 16        // nodes per block (4 waves x 4 nodes) in fused layers

typedef unsigned int uint32;
typedef unsigned short ushort;
using short8 = __attribute__((ext_vector_type(8))) short;
using f32x4  = __attribute__((ext_vector_type(4))) float;

// fp16 pack/unpack helpers (RNE via v_cvt)
__device__ __forceinline__ float2 h2f2(uint32 u) {
    __half2 h = *(__half2*)&u;
    return __half22float2(h);
}
__device__ __forceinline__ uint32 f2h2(float a, float b) {
    __half2 h;
    h.x = __float2half(a);
    h.y = __float2half(b);
    return *(uint32*)&h;
}

// unpack one fp16x8 row chunk and accumulate into 8 fp32 lane-cols
__device__ __forceinline__ void accum4(float* acc, uint4 v) {
    float2 e0 = h2f2(v.x), e1 = h2f2(v.y), e2 = h2f2(v.z), e3 = h2f2(v.w);
    acc[0] += e0.x; acc[1] += e0.y; acc[2] += e1.x; acc[3] += e1.y;
    acc[4] += e2.x; acc[5] += e2.y; acc[6] += e3.x; acc[7] += e3.y;
}

// ---------------------------------------------------------------------------
// setup: fill=0, zero fp16 pad row (row n) of BOTH gather planes (S1, S2),
// zero pooled (fp32, for pool_partial atomics), and build gstart[0..NGRAPH]
// segment-boundary table from sorted batch.
// ---------------------------------------------------------------------------
__global__ void setup(int* __restrict__ fill, uint32* __restrict__ s1,
                      uint32* __restrict__ s2, const int* __restrict__ batch,
                      int* __restrict__ gstart, float* __restrict__ pooled, int n) {
    int i = blockIdx.x * blockDim.x + threadIdx.x;
    if (i < n) fill[i] = 0;
    if (i < 64) {
        s1[(size_t)n * 64 + i] = 0u;     // zero pad row of layer-1 plane
        s2[(size_t)n * 64 + i] = 0u;     // zero pad row of layer-2 plane
    }
    if (i < NGRAPH * HID) pooled[i] = 0.f;
    if (i < n) {
        int b0 = batch[i];
        if (i == 0) {
            for (int g = 0; g <= b0; ++g) gstart[g] = 0;   // leading (possibly empty)
        }
        if (i + 1 < n) {
            int b1 = batch[i + 1];
            for (int g = b0 + 1; g <= b1; ++g) gstart[g] = i + 1;
        } else {
            for (int g = b0 + 1; g <= NGRAPH; ++g) gstart[g] = n;  // trailing
        }
    }
}

// ---------------------------------------------------------------------------
// capacity-CSR fill + weight pack fused (single atomic pass, no scan).
// blocks [0,EB): pos = fill[dst]++ ; csr[dst*CAP+pos] = src (NT store: the
// random 4B scatter into the 12.8 MB CSR otherwise pays read-for-ownership
// on every 64B line — nt skips L2 allocation; later reads refetch ~2.4MB/layer
// which is cheaper than the RFO traffic).
// blocks [EB,EB+128): pack W2,W3 -> transposed single-plane fp16 wt[sel][n][k].
// NOTE: int (not ushort) CSR deliberately — the ushort variant core-dumped
// on HW in a previous round.
// ---------------------------------------------------------------------------
__global__ void csr_fill_pack(const int* __restrict__ src, const int* __restrict__ dst,
                              int* __restrict__ fill, int* __restrict__ csr,
                              int E, int EB,
                              const float* __restrict__ W2, const float* __restrict__ W3,
                              ushort* __restrict__ wt) {
    int b = blockIdx.x;
    if (b < EB) {
        int e = b * blockDim.x + threadIdx.x;
        if (e >= E) return;
        int d = dst[e];
        int pos = atomicAdd(&fill[d], 1);
        if (pos < CAP)
            __builtin_nontemporal_store(src[e], &csr[(size_t)d * CAP + pos]);
    } else {
        int t = (b - EB) * blockDim.x + threadIdx.x;   // 0..32767
        int sel = t >> 14;                             // 0: W2, 1: W3
        int idx = t & 16383;
        int nn = idx >> 7, kk = idx & 127;
        const float* W = sel ? W3 : W2;
        wt[sel * 16384 + idx] = __half_as_ushort(__float2half(W[kk * HID + nn]));
    }
}

// ---------------------------------------------------------------------------
// finalize: dis = 1/sqrt(deg) with deg = fill+1 (self-loop); pack
// xp[i] = dis[i] * x[i,:] into 32 B rows (vector-gatherable by layer 1).
// ---------------------------------------------------------------------------
__global__ void finalize(const int* __restrict__ fill, float* __restrict__ dis,
                         const float* __restrict__ x, float4* __restrict__ xp4, int n) {
    int i = blockIdx.x * blockDim.x + threadIdx.x;
    if (i >= n) return;
    int d = fill[i] + 1;
    float di = (float)(1.0 / sqrt((double)d));
    dis[i] = di;
    const float* xi = x + (size_t)i * 6;
    xp4[(size_t)i * 2]     = make_float4(di * xi[0], di * xi[1], di * xi[2], di * xi[3]);
    xp4[(size_t)i * 2 + 1] = make_float4(di * xi[4], di * xi[5], 0.f, 0.f);
}

// ---------------------------------------------------------------------------
// layer 1 (R12-proven): FOUR nodes per wave (16-lane group per node).
// Lane sl handles edge slots sl, sl+16, sl+32, sl+48; self-loop folded in;
// reduce = 4 butterfly steps over 16 lanes; each lane emits 8 cols of
// S1 = dis*relu(xa@W1+b1) as one uint4 store.
// ---------------------------------------------------------------------------
__global__ __launch_bounds__(256) void layer1_quad(
    const float4* __restrict__ xp4, const int* __restrict__ fill,
    const int* __restrict__ csr, const float* __restrict__ dis,
    const float* __restrict__ W1, const float* __restrict__ b1,
    uint32* __restrict__ S1, int n) {
    int t = blockIdx.x * blockDim.x + threadIdx.x;
    int wv = t >> 6;                 // wave id
    int lane = t & 63;
    int sub = lane >> 4;             // node slot within wave (0..3)
    int sl  = lane & 15;             // lane slot within node
    int i = wv * 4 + sub;
    if (i >= n) return;              // whole 16-lane group exits together

    int m = fill[i]; if (m > CAP) m = CAP;
    float a0 = 0.f, a1 = 0.f, a2 = 0.f, a3 = 0.f, a4 = 0.f, a5 = 0.f;
#pragma unroll
    for (int r = 0; r < 4; ++r) {
        int slot = sl + 16 * r;
        if (slot < m) {
            int s = csr[(size_t)i * CAP + slot];
            float4 p0 = xp4[(size_t)s * 2];
            float4 p1 = xp4[(size_t)s * 2 + 1];
            a0 += p0.x; a1 += p0.y; a2 += p0.z;
            a3 += p0.w; a4 += p1.x; a5 += p1.y;
        }
    }
    // butterfly reduce within the 16-lane group (offsets stay in-group)
#pragma unroll
    for (int off = 8; off > 0; off >>= 1) {
        a0 += __shfl_xor(a0, off); a1 += __shfl_xor(a1, off);
        a2 += __shfl_xor(a2, off); a3 += __shfl_xor(a3, off);
        a4 += __shfl_xor(a4, off); a5 += __shfl_xor(a5, off);
    }
    float di = dis[i];
    float4 s0 = xp4[(size_t)i * 2];
    float4 s1v = xp4[(size_t)i * 2 + 1];
    float xa[6];
    xa[0] = di * (s0.x + a0); xa[1] = di * (s0.y + a1);
    xa[2] = di * (s0.z + a2); xa[3] = di * (s0.w + a3);
    xa[4] = di * (s1v.x + a4); xa[5] = di * (s1v.y + a5);

    int c0 = sl * 8;                 // this lane's 8 output cols
    float z[8];
#pragma unroll
    for (int j = 0; j < 8; ++j) z[j] = b1[c0 + j];
#pragma unroll
    for (int k = 0; k < 6; ++k) {
#pragma unroll
        for (int j = 0; j < 8; ++j) z[j] += xa[k] * W1[k * HID + c0 + j];
    }
    uint4 h4 = make_uint4(f2h2(di * fmaxf(z[0], 0.f), di * fmaxf(z[1], 0.f)),
                          f2h2(di * fmaxf(z[2], 0.f), di * fmaxf(z[3], 0.f)),
                          f2h2(di * fmaxf(z[4], 0.f), di * fmaxf(z[5], 0.f)),
                          f2h2(di * fmaxf(z[6], 0.f), di * fmaxf(z[7], 0.f)));
    *(uint4*)(S1 + (size_t)i * 64 + sl * 4) = h4;
}

// ---------------------------------------------------------------------------
// FUSED GCN layer (layers 2 & 3): aggregate-then-GEMM.  R10-PROVEN CONFIG
// (16 nodes/block, 4/wave, simple 2-pair body with 8 uint4 in flight).
// ILP-deepening past 8 is source-unreachable: R8 sink (VGPR 60), R9 spill
// (MINW=8 -> VGPR 32 + 77MB scratch), R11 fence -> partial spill. Do not
// revisit.
// ---------------------------------------------------------------------------
template<int MINW>
__global__ __launch_bounds__(256, MINW) void layer_agg_gemm(
    const uint32* __restrict__ Sin, const int* __restrict__ fill,
    const int* __restrict__ csr, const float* __restrict__ dis,
    const ushort* __restrict__ WT, const float* __restrict__ bias,
    uint32* __restrict__ Sout, int n, int scaleOut) {
    __shared__ uint4 plds4[NPB * 17];           // 16 rows x 272 B = 4352 B
    const int wave = threadIdx.x >> 6;
    const int lane = threadIdx.x & 63;
    const int grp = lane >> 4;                  // edge-slot group 0..3
    const int q   = lane & 15;                  // uint4 col chunk (8 fp16)
    const int blk0 = blockIdx.x * NPB;
    const int base = blk0 + wave * 4;

    // ---- prologue: prefetch fill + csr index vectors for the 4 nodes ----
    int mt4[4];    // edge count incl. appended self-loop (<= 64)
    int idx4[4];   // this lane's edge slot for node j (pad -> zero row n)
#pragma unroll
    for (int j = 0; j < 4; ++j) {
        int i = base + j;
        int fv = (i < n) ? fill[i] : 0;
        int m = fv > CAP ? CAP : fv;
        idx4[j] = (lane < m) ? csr[(size_t)i * CAP + lane]
                             : ((lane == m && i < n && m < CAP) ? i : n);
        mt4[j] = m + (m < CAP ? 1 : 0);   // append self as slot m
    }

    // ---- phase A: paired gather-aggregate into LDS (2 pairs) ----
#pragma unroll
    for (int jp = 0; jp < 2; ++jp) {
        const int ja = jp * 2, jb = ja + 1;
        float acca[8] = {0.f, 0.f, 0.f, 0.f, 0.f, 0.f, 0.f, 0.f};
        float accb[8] = {0.f, 0.f, 0.f, 0.f, 0.f, 0.f, 0.f, 0.f};
        // first 16-edge round of BOTH nodes co-issued (8 uint4 in flight)
        {
            int sa1 = __shfl(idx4[ja], grp);
            int sa2 = __shfl(idx4[ja], 4 + grp);
            int sa3 = __shfl(idx4[ja], 8 + grp);
            int sa4 = __shfl(idx4[ja], 12 + grp);
            int sb1 = __shfl(idx4[jb], grp);
            int sb2 = __shfl(idx4[jb], 4 + grp);
            int sb3 = __shfl(idx4[jb], 8 + grp);
            int sb4 = __shfl(idx4[jb], 12 + grp);
            uint4 va1 = *(const uint4*)(Sin + (size_t)sa1 * 64 + q * 4);
            uint4 va2 = *(const uint4*)(Sin + (size_t)sa2 * 64 + q * 4);
            uint4 va3 = *(const uint4*)(Sin + (size_t)sa3 * 64 + q * 4);
            uint4 va4 = *(const uint4*)(Sin + (size_t)sa4 * 64 + q * 4);
            uint4 vb1 = *(const uint4*)(Sin + (size_t)sb1 * 64 + q * 4);
            uint4 vb2 = *(const uint4*)(Sin + (size_t)sb2 * 64 + q * 4);
            uint4 vb3 = *(const uint4*)(Sin + (size_t)sb3 * 64 + q * 4);
            uint4 vb4 = *(const uint4*)(Sin + (size_t)sb4 * 64 + q * 4);
            accum4(acca, va1); accum4(acca, va2);
            accum4(acca, va3); accum4(acca, va4);
            accum4(accb, vb1); accum4(accb, vb2);
            accum4(accb, vb3); accum4(accb, vb4);
        }
        // remainder rounds (m >= 16), serial per node
        for (int k = 16; k < mt4[ja]; k += 16) {
            int s1 = __shfl(idx4[ja], k + grp);
            int s2 = __shfl(idx4[ja], k + 4 + grp);
            int s3 = __shfl(idx4[ja], k + 8 + grp);
            int s4 = __shfl(idx4[ja], k + 12 + grp);
            uint4 v1 = *(const uint4*)(Sin + (size_t)s1 * 64 + q * 4);
            uint4 v2 = *(const uint4*)(Sin + (size_t)s2 * 64 + q * 4);
            uint4 v3 = *(const uint4*)(Sin + (size_t)s3 * 64 + q * 4);
            uint4 v4 = *(const uint4*)(Sin + (size_t)s4 * 64 + q * 4);
            accum4(acca, v1); accum4(acca, v2);
            accum4(acca, v3); accum4(acca, v4);
        }
        for (int k = 16; k < mt4[jb]; k += 16) {
            int s1 = __shfl(idx4[jb], k + grp);
            int s2 = __shfl(idx4[jb], k + 4 + grp);
            int s3 = __shfl(idx4[jb], k + 8 + grp);
            int s4 = __shfl(idx4[jb], k + 12 + grp);
            uint4 v1 = *(const uint4*)(Sin + (size_t)s1 * 64 + q * 4);
            uint4 v2 = *(const uint4*)(Sin + (size_t)s2 * 64 + q * 4);
            uint4 v3 = *(const uint4*)(Sin + (size_t)s3 * 64 + q * 4);
            uint4 v4 = *(const uint4*)(Sin + (size_t)s4 * 64 + q * 4);
            accum4(accb, v1); accum4(accb, v2);
            accum4(accb, v3); accum4(accb, v4);
        }
        // cross-group butterfly reduce (4 groups -> full row sums)
#pragma unroll
        for (int r = 0; r < 8; ++r) {
            acca[r] += __shfl_xor(acca[r], 16);
            acca[r] += __shfl_xor(acca[r], 32);
            accb[r] += __shfl_xor(accb[r], 16);
            accb[r] += __shfl_xor(accb[r], 32);
        }
        if (grp == 0) {
            int ia = base + ja, ib = base + jb;
            float da = (ia < n) ? dis[ia] : 0.f;
            float db = (ib < n) ? dis[ib] : 0.f;
            plds4[(wave * 4 + ja) * 17 + q] =
                make_uint4(f2h2(da * acca[0], da * acca[1]),
                           f2h2(da * acca[2], da * acca[3]),
                           f2h2(da * acca[4], da * acca[5]),
                           f2h2(da * acca[6], da * acca[7]));
            plds4[(wave * 4 + jb) * 17 + q] =
                make_uint4(f2h2(db * accb[0], db * accb[1]),
                           f2h2(db * accb[2], db * accb[3]),
                           f2h2(db * accb[4], db * accb[5]),
                           f2h2(db * accb[6], db * accb[7]));
        }
    }
    __syncthreads();

    // ---- phase B: 16x128 GEMM out = [dis*] relu(P @ W + b) ----
    // wave w owns cols [w*32, w*32+32); 16 rows; 8 MFMA per wave.
    const int l16 = lane & 15, quad = lane >> 4;
    f32x4 acc2[2] = {};
#pragma unroll
    for (int kc = 0; kc < 4; ++kc) {
        int ko = kc * 32 + quad * 8;
        short8 a0 = *(const short8*)&plds4[(size_t)l16 * 17 + kc * 4 + quad];
#pragma unroll
        for (int ct = 0; ct < 2; ++ct) {
            short8 wh = *(const short8*)(WT + (size_t)(wave * 32 + ct * 16 + l16) * HID + ko);
            acc2[ct] = __builtin_amdgcn_mfma_f32_16x16x32_f16(wh, a0, acc2[ct], 0, 0, 0);
        }
    }
    ushort* so = (ushort*)Sout;
    int node = blk0 + l16;
    if (node < n) {
        float sc = scaleOut ? dis[node] : 1.f;
#pragma unroll
        for (int ct = 0; ct < 2; ++ct) {
            int cb = wave * 32 + ct * 16 + quad * 4;
            float4 bv = *(const float4*)(bias + cb);
            float o0 = fmaxf(acc2[ct][0] + bv.x, 0.f) * sc;
            float o1 = fmaxf(acc2[ct][1] + bv.y, 0.f) * sc;
            float o2 = fmaxf(acc2[ct][2] + bv.z, 0.f) * sc;
            float o3 = fmaxf(acc2[ct][3] + bv.w, 0.f) * sc;
            *(uint2*)(so + (size_t)node * HID + cb) = make_uint2(f2h2(o0, o1), f2h2(o2, o3));
        }
    }
}

// ---------------------------------------------------------------------------
// pool_partial (R13): 8 row-chunks per graph -> 512 blocks (was 64 = 1 block
// per 4 CUs, 75% of the chip idle). Block (g,c) streams its chunk of rows,
// LDS cross-wave reduce, one fp32 atomicAdd per column into pooled[g][128].
// ---------------------------------------------------------------------------
__global__ __launch_bounds__(256) void pool_partial(
    const uint32* __restrict__ h, const int* __restrict__ gstart,
    float* __restrict__ pooled, int n) {
    __shared__ float red[4][128];
    const int g = blockIdx.x >> 3;
    const int c = blockIdx.x & 7;
    const int t = threadIdx.x;
    const int sub = t >> 6, cc = t & 63;

    const int start = gstart[g], end = gstart[g + 1];
    const int len = end - start;
    const int s0 = start + (int)(((long)len * c) >> 3);
    const int s1 = start + (int)(((long)len * (c + 1)) >> 3);

    float sx = 0.f, sy = 0.f;
    int i = s0 + sub;
    for (; i + 12 < s1; i += 16) {        // 4 rows x unroll 4 in flight
        uint32 u0 = h[(size_t)i * 64 + cc];
        uint32 u1 = h[(size_t)(i + 4) * 64 + cc];
        uint32 u2 = h[(size_t)(i + 8) * 64 + cc];
        uint32 u3 = h[(size_t)(i + 12) * 64 + cc];
        float2 v0 = h2f2(u0), v1 = h2f2(u1), v2 = h2f2(u2), v3 = h2f2(u3);
        sx += v0.x + v1.x + v2.x + v3.x;
        sy += v0.y + v1.y + v2.y + v3.y;
    }
    for (; i < s1; i += 4) {
        float2 v = h2f2(h[(size_t)i * 64 + cc]);
        sx += v.x; sy += v.y;
    }
    *(float2*)&red[sub][2 * cc] = make_float2(sx, sy);
    __syncthreads();

    if (t < 128) {
        float v = red[0][t] + red[1][t] + red[2][t] + red[3][t];
        atomicAdd(&pooled[g * HID + t], v);
    }
}

// ---------------------------------------------------------------------------
// MLP head: 64 blocks x 64 threads; mean from gstart counts.
// ---------------------------------------------------------------------------
__global__ void mlp_head(const float* __restrict__ pooled, const int* __restrict__ gstart,
                         const float* __restrict__ fc1w, const float* __restrict__ fc1b,
                         const float* __restrict__ fc2w, const float* __restrict__ fc2b,
                         float* __restrict__ out) {
    int g = blockIdx.x;
    int j = threadIdx.x;
    float inv = 1.0f / fmaxf((float)(gstart[g + 1] - gstart[g]), 1.0f);
    float z = fc1b[j];
#pragma unroll 8
    for (int k = 0; k < HID; ++k) z += (pooled[g * HID + k] * inv) * fc1w[k * 64 + j];
    z = fmaxf(z, 0.f);
    float v = z * fc2w[j];
#pragma unroll
    for (int off = 32; off > 0; off >>= 1) v += __shfl_down(v, off);
    if (j == 0) out[g] = v + fc2b[0];
}

// ---------------------------------------------------------------------------
extern "C" void kernel_launch(void* const* d_in, const int* in_sizes, int n_in,
                              void* d_out, int out_size, void* d_ws, size_t ws_size,
                              hipStream_t stream) {
    const float* x     = (const float*)d_in[0];
    const int*   ei    = (const int*)d_in[1];
    const int*   batch = (const int*)d_in[2];
    const float* W1    = (const float*)d_in[3];
    const float* b1    = (const float*)d_in[4];
    const float* W2    = (const float*)d_in[5];
    const float* b2    = (const float*)d_in[6];
    const float* W3    = (const float*)d_in[7];
    const float* b3    = (const float*)d_in[8];
    const float* fc1w  = (const float*)d_in[9];
    const float* fc1b  = (const float*)d_in[10];
    const float* fc2w  = (const float*)d_in[11];
    const float* fc2b  = (const float*)d_in[12];
    float* out = (float*)d_out;

    const int N = in_sizes[0] / 6;   // 50000
    const int E = in_sizes[1] / 2;   // 600000
    const int* src = ei;
    const int* dst = ei + E;

    char* ws = (char*)d_ws;
    char* p = ws;
    uint32* S1   = (uint32*)p;   p += (size_t)(N + 1) * 256;      // dis*h1 fp16 plane (+pad row)
    uint32* S2   = (uint32*)p;   p += (size_t)(N + 1) * 256;      // dis*h2 fp16 plane (+pad row)
    uint32* B1h  = (uint32*)p;   p += (size_t)N * 256;            // fp16 final acts (h3)
    float4* xp4  = (float4*)p;   p += (size_t)N * 32;             // dis-scaled x rows
    ushort* WT   = (ushort*)p;   p += 2 * 32768;                  // packed W2,W3 (fp16)
    float* dis     = (float*)p;  p += (size_t)N * 4;
    int*   fill    = (int*)p;    p += (size_t)N * 4;
    int*   csr     = (int*)p;    p += (size_t)N * CAP * 4;        // capacity CSR
    int*   gstart  = (int*)p;    p += (NGRAPH + 1) * 4;           // pool segment bounds
    float* pooled  = (float*)p;  p += NGRAPH * HID * 4;           // fp32 pool accum

    const int B = 256;
    const int EB = (E + B - 1) / B;

    // ---- setup + capacity-CSR build (no count pass, no scan) ----
    setup<<<(N + B - 1) / B, B, 0, stream>>>(fill, S1, S2, batch, gstart, pooled, N);
    csr_fill_pack<<<EB + 128, B, 0, stream>>>(src, dst, fill, csr, E, EB, W2, W3, WT);
    finalize<<<(N + B - 1) / B, B, 0, stream>>>(fill, dis, x, xp4, N);

    int l1Blocks = (int)(((size_t)N * 16 + B - 1) / B);    // 4 nodes/wave
    int fusedBlocks = (N + NPB - 1) / NPB;

    // ---- layer 1 (4 nodes/wave, fused aggregate + GEMV + relu + dis-scale) ----
    layer1_quad<<<l1Blocks, B, 0, stream>>>(xp4, fill, csr, dis, W1, b1, S1, N);

    // ---- layer 2: fused (A*S1) then @W2 (+b2, relu, *dis) -> S2 ----
    layer_agg_gemm<6><<<fusedBlocks, B, 0, stream>>>(S1, fill, csr, dis, WT, b2, S2, N, 1);

    // ---- layer 3: fused (A*S2) then @W3 (+b3, relu) -> B1h (unscaled) ----
    layer_agg_gemm<5><<<fusedBlocks, B, 0, stream>>>(S2, fill, csr, dis, WT + 16384, b3, B1h, N, 0);

    // ---- pool: 512 blocks (8 chunks/graph) -> fp32 atomics ----
    pool_partial<<<NGRAPH * 8, B, 0, stream>>>(B1h, gstart, pooled, N);

    // ---- head ----
    mlp_head<<<NGRAPH, 64, 0, stream>>>(pooled, gstart, fc1w, fc1b, fc2w, fc2b, out);
}

// Round 14
// 212.197 us; speedup vs baseline: 1.1725x; 1.0324x over previous
//
#include <hip/hip_runtime.h>
#include <hip/hip_fp16.h>

#define HID 128
#define NGRAPH 64
#define CAP 64        // fixed CSR capacity per row (Poisson lambda=12 -> safe)
#define NPB 16        // nodes per block (4 waves x 4 nodes) in fused layers

typedef unsigned int uint32;
typedef unsigned short ushort;
using short8 = __attribute__((ext_vector_type(8))) short;
using f32x4  = __attribute__((ext_vector_type(4))) float;

// fp16 pack/unpack helpers (RNE via v_cvt)
__device__ __forceinline__ float2 h2f2(uint32 u) {
    __half2 h = *(__half2*)&u;
    return __half22float2(h);
}
__device__ __forceinline__ uint32 f2h2(float a, float b) {
    __half2 h;
    h.x = __float2half(a);
    h.y = __float2half(b);
    return *(uint32*)&h;
}

// unpack one fp16x8 row chunk and accumulate into 8 fp32 lane-cols
__device__ __forceinline__ void accum4(float* acc, uint4 v) {
    float2 e0 = h2f2(v.x), e1 = h2f2(v.y), e2 = h2f2(v.z), e3 = h2f2(v.w);
    acc[0] += e0.x; acc[1] += e0.y; acc[2] += e1.x; acc[3] += e1.y;
    acc[4] += e2.x; acc[5] += e2.y; acc[6] += e3.x; acc[7] += e3.y;
}

// ---- gather-row abstraction: fp16 (uint4, 256B rows) vs fp8 (uint2, 128B) --
template<bool F8> struct RowVec;
template<> struct RowVec<false> { uint4 v; };
template<> struct RowVec<true>  { uint2 v; };

template<bool F8>
__device__ __forceinline__ RowVec<F8> ldrow(const uint32* __restrict__ S, int s, int q) {
    RowVec<F8> r;
    if constexpr (F8) r.v = *(const uint2*)(S + (size_t)s * 32 + q * 2);
    else              r.v = *(const uint4*)(S + (size_t)s * 64 + q * 4);
    return r;
}
template<bool F8>
__device__ __forceinline__ void acc8(float* a, RowVec<F8> r) {
    if constexpr (F8) {
        auto e0 = __builtin_amdgcn_cvt_pk_f32_fp8(r.v.x, false);
        auto e1 = __builtin_amdgcn_cvt_pk_f32_fp8(r.v.x, true);
        auto e2 = __builtin_amdgcn_cvt_pk_f32_fp8(r.v.y, false);
        auto e3 = __builtin_amdgcn_cvt_pk_f32_fp8(r.v.y, true);
        a[0] += e0[0]; a[1] += e0[1]; a[2] += e1[0]; a[3] += e1[1];
        a[4] += e2[0]; a[5] += e2[1]; a[6] += e3[0]; a[7] += e3[1];
    } else {
        accum4(a, r.v);
    }
}

// ---------------------------------------------------------------------------
// setup: fill=0, zero pad rows (S1 fp8: 32 u32; S2 fp16: 64 u32), zero
// pooled, and build gstart[0..NGRAPH] from sorted batch.
// ---------------------------------------------------------------------------
__global__ void setup(int* __restrict__ fill, uint32* __restrict__ s1,
                      uint32* __restrict__ s2, const int* __restrict__ batch,
                      int* __restrict__ gstart, float* __restrict__ pooled, int n) {
    int i = blockIdx.x * blockDim.x + threadIdx.x;
    if (i < n) fill[i] = 0;
    if (i < 32) s1[(size_t)n * 32 + i] = 0u;   // fp8 pad row (128 B)
    if (i < 64) s2[(size_t)n * 64 + i] = 0u;   // fp16 pad row (256 B)
    if (i < NGRAPH * HID) pooled[i] = 0.f;
    if (i < n) {
        int b0 = batch[i];
        if (i == 0) {
            for (int g = 0; g <= b0; ++g) gstart[g] = 0;   // leading (possibly empty)
        }
        if (i + 1 < n) {
            int b1 = batch[i + 1];
            for (int g = b0 + 1; g <= b1; ++g) gstart[g] = i + 1;
        } else {
            for (int g = b0 + 1; g <= NGRAPH; ++g) gstart[g] = n;  // trailing
        }
    }
}

// ---------------------------------------------------------------------------
// capacity-CSR fill + weight pack fused (single atomic pass, no scan).
// CSR scatter uses NT store (skips L2 RFO on the random 4B scatter — R13 win).
// NOTE: int (not ushort) CSR deliberately — ushort variant core-dumped on HW.
// ---------------------------------------------------------------------------
__global__ void csr_fill_pack(const int* __restrict__ src, const int* __restrict__ dst,
                              int* __restrict__ fill, int* __restrict__ csr,
                              int E, int EB,
                              const float* __restrict__ W2, const float* __restrict__ W3,
                              ushort* __restrict__ wt) {
    int b = blockIdx.x;
    if (b < EB) {
        int e = b * blockDim.x + threadIdx.x;
        if (e >= E) return;
        int d = dst[e];
        int pos = atomicAdd(&fill[d], 1);
        if (pos < CAP)
            __builtin_nontemporal_store(src[e], &csr[(size_t)d * CAP + pos]);
    } else {
        int t = (b - EB) * blockDim.x + threadIdx.x;   // 0..32767
        int sel = t >> 14;                             // 0: W2, 1: W3
        int idx = t & 16383;
        int nn = idx >> 7, kk = idx & 127;
        const float* W = sel ? W3 : W2;
        wt[sel * 16384 + idx] = __half_as_ushort(__float2half(W[kk * HID + nn]));
    }
}

// ---------------------------------------------------------------------------
// finalize: dis = 1/sqrt(deg) with deg = fill+1 (self-loop); pack
// xp[i] = dis[i] * x[i,:] into 32 B rows (vector-gatherable by layer 1).
// ---------------------------------------------------------------------------
__global__ void finalize(const int* __restrict__ fill, float* __restrict__ dis,
                         const float* __restrict__ x, float4* __restrict__ xp4, int n) {
    int i = blockIdx.x * blockDim.x + threadIdx.x;
    if (i >= n) return;
    int d = fill[i] + 1;
    float di = (float)(1.0 / sqrt((double)d));
    dis[i] = di;
    const float* xi = x + (size_t)i * 6;
    xp4[(size_t)i * 2]     = make_float4(di * xi[0], di * xi[1], di * xi[2], di * xi[3]);
    xp4[(size_t)i * 2 + 1] = make_float4(di * xi[4], di * xi[5], 0.f, 0.f);
}

// ---------------------------------------------------------------------------
// layer 1 (R12-proven structure): FOUR nodes per wave (16-lane group/node).
// R14: output plane S1 is fp8 e4m3 (128 B rows) — halves layer 2's gather
// cache-line count. Each lane packs its 8 cols via HW cvt_pk_fp8 (RNE).
// ---------------------------------------------------------------------------
__global__ __launch_bounds__(256) void layer1_quad(
    const float4* __restrict__ xp4, const int* __restrict__ fill,
    const int* __restrict__ csr, const float* __restrict__ dis,
    const float* __restrict__ W1, const float* __restrict__ b1,
    uint32* __restrict__ S1, int n) {
    int t = blockIdx.x * blockDim.x + threadIdx.x;
    int wv = t >> 6;                 // wave id
    int lane = t & 63;
    int sub = lane >> 4;             // node slot within wave (0..3)
    int sl  = lane & 15;             // lane slot within node
    int i = wv * 4 + sub;
    if (i >= n) return;              // whole 16-lane group exits together

    int m = fill[i]; if (m > CAP) m = CAP;
    float a0 = 0.f, a1 = 0.f, a2 = 0.f, a3 = 0.f, a4 = 0.f, a5 = 0.f;
#pragma unroll
    for (int r = 0; r < 4; ++r) {
        int slot = sl + 16 * r;
        if (slot < m) {
            int s = csr[(size_t)i * CAP + slot];
            float4 p0 = xp4[(size_t)s * 2];
            float4 p1 = xp4[(size_t)s * 2 + 1];
            a0 += p0.x; a1 += p0.y; a2 += p0.z;
            a3 += p0.w; a4 += p1.x; a5 += p1.y;
        }
    }
    // butterfly reduce within the 16-lane group (offsets stay in-group)
#pragma unroll
    for (int off = 8; off > 0; off >>= 1) {
        a0 += __shfl_xor(a0, off); a1 += __shfl_xor(a1, off);
        a2 += __shfl_xor(a2, off); a3 += __shfl_xor(a3, off);
        a4 += __shfl_xor(a4, off); a5 += __shfl_xor(a5, off);
    }
    float di = dis[i];
    float4 s0 = xp4[(size_t)i * 2];
    float4 s1v = xp4[(size_t)i * 2 + 1];
    float xa[6];
    xa[0] = di * (s0.x + a0); xa[1] = di * (s0.y + a1);
    xa[2] = di * (s0.z + a2); xa[3] = di * (s0.w + a3);
    xa[4] = di * (s1v.x + a4); xa[5] = di * (s1v.y + a5);

    int c0 = sl * 8;                 // this lane's 8 output cols
    float z[8];
#pragma unroll
    for (int j = 0; j < 8; ++j) z[j] = b1[c0 + j];
#pragma unroll
    for (int k = 0; k < 6; ++k) {
#pragma unroll
        for (int j = 0; j < 8; ++j) z[j] += xa[k] * W1[k * HID + c0 + j];
    }
    float o[8];
#pragma unroll
    for (int j = 0; j < 8; ++j) o[j] = di * fmaxf(z[j], 0.f);
    uint32 r0 = 0, r1 = 0;
    r0 = __builtin_amdgcn_cvt_pk_fp8_f32(o[0], o[1], r0, false);
    r0 = __builtin_amdgcn_cvt_pk_fp8_f32(o[2], o[3], r0, true);
    r1 = __builtin_amdgcn_cvt_pk_fp8_f32(o[4], o[5], r1, false);
    r1 = __builtin_amdgcn_cvt_pk_fp8_f32(o[6], o[7], r1, true);
    *(uint2*)(S1 + (size_t)i * 32 + sl * 2) = make_uint2(r0, r1);
}

// ---------------------------------------------------------------------------
// FUSED GCN layer: aggregate-then-GEMM. R10-proven structure (16 nodes/blk,
// 4/wave, 2-pair body, 8 row-loads in flight). F8IN selects the input plane
// format: fp8 e4m3 128 B rows (layer 2) vs fp16 256 B rows (layer 3) —
// within-run A/B on the cache-line-count hypothesis.
// ILP-deepening past 8 is source-unreachable (R8 sink / R9 spill / R11
// fence->partial spill). Do not revisit.
// ---------------------------------------------------------------------------
template<int MINW, bool F8IN>
__global__ __launch_bounds__(256, MINW) void layer_agg_gemm(
    const uint32* __restrict__ Sin, const int* __restrict__ fill,
    const int* __restrict__ csr, const float* __restrict__ dis,
    const ushort* __restrict__ WT, const float* __restrict__ bias,
    uint32* __restrict__ Sout, int n, int scaleOut) {
    __shared__ uint4 plds4[NPB * 17];           // 16 rows x 272 B = 4352 B
    const int wave = threadIdx.x >> 6;
    const int lane = threadIdx.x & 63;
    const int grp = lane >> 4;                  // edge-slot group 0..3
    const int q   = lane & 15;                  // col chunk (8 values)
    const int blk0 = blockIdx.x * NPB;
    const int base = blk0 + wave * 4;

    // ---- prologue: prefetch fill + csr index vectors for the 4 nodes ----
    int mt4[4];    // edge count incl. appended self-loop (<= 64)
    int idx4[4];   // this lane's edge slot for node j (pad -> zero row n)
#pragma unroll
    for (int j = 0; j < 4; ++j) {
        int i = base + j;
        int fv = (i < n) ? fill[i] : 0;
        int m = fv > CAP ? CAP : fv;
        idx4[j] = (lane < m) ? csr[(size_t)i * CAP + lane]
                             : ((lane == m && i < n && m < CAP) ? i : n);
        mt4[j] = m + (m < CAP ? 1 : 0);   // append self as slot m
    }

    // ---- phase A: paired gather-aggregate into LDS (2 pairs) ----
#pragma unroll
    for (int jp = 0; jp < 2; ++jp) {
        const int ja = jp * 2, jb = ja + 1;
        float acca[8] = {0.f, 0.f, 0.f, 0.f, 0.f, 0.f, 0.f, 0.f};
        float accb[8] = {0.f, 0.f, 0.f, 0.f, 0.f, 0.f, 0.f, 0.f};
        // first 16-edge round of BOTH nodes co-issued (8 row-loads in flight)
        {
            int sa1 = __shfl(idx4[ja], grp);
            int sa2 = __shfl(idx4[ja], 4 + grp);
            int sa3 = __shfl(idx4[ja], 8 + grp);
            int sa4 = __shfl(idx4[ja], 12 + grp);
            int sb1 = __shfl(idx4[jb], grp);
            int sb2 = __shfl(idx4[jb], 4 + grp);
            int sb3 = __shfl(idx4[jb], 8 + grp);
            int sb4 = __shfl(idx4[jb], 12 + grp);
            RowVec<F8IN> va1 = ldrow<F8IN>(Sin, sa1, q);
            RowVec<F8IN> va2 = ldrow<F8IN>(Sin, sa2, q);
            RowVec<F8IN> va3 = ldrow<F8IN>(Sin, sa3, q);
            RowVec<F8IN> va4 = ldrow<F8IN>(Sin, sa4, q);
            RowVec<F8IN> vb1 = ldrow<F8IN>(Sin, sb1, q);
            RowVec<F8IN> vb2 = ldrow<F8IN>(Sin, sb2, q);
            RowVec<F8IN> vb3 = ldrow<F8IN>(Sin, sb3, q);
            RowVec<F8IN> vb4 = ldrow<F8IN>(Sin, sb4, q);
            acc8<F8IN>(acca, va1); acc8<F8IN>(acca, va2);
            acc8<F8IN>(acca, va3); acc8<F8IN>(acca, va4);
            acc8<F8IN>(accb, vb1); acc8<F8IN>(accb, vb2);
            acc8<F8IN>(accb, vb3); acc8<F8IN>(accb, vb4);
        }
        // remainder rounds (m >= 16), serial per node
        for (int k = 16; k < mt4[ja]; k += 16) {
            int s1 = __shfl(idx4[ja], k + grp);
            int s2 = __shfl(idx4[ja], k + 4 + grp);
            int s3 = __shfl(idx4[ja], k + 8 + grp);
            int s4 = __shfl(idx4[ja], k + 12 + grp);
            RowVec<F8IN> v1 = ldrow<F8IN>(Sin, s1, q);
            RowVec<F8IN> v2 = ldrow<F8IN>(Sin, s2, q);
            RowVec<F8IN> v3 = ldrow<F8IN>(Sin, s3, q);
            RowVec<F8IN> v4 = ldrow<F8IN>(Sin, s4, q);
            acc8<F8IN>(acca, v1); acc8<F8IN>(acca, v2);
            acc8<F8IN>(acca, v3); acc8<F8IN>(acca, v4);
        }
        for (int k = 16; k < mt4[jb]; k += 16) {
            int s1 = __shfl(idx4[jb], k + grp);
            int s2 = __shfl(idx4[jb], k + 4 + grp);
            int s3 = __shfl(idx4[jb], k + 8 + grp);
            int s4 = __shfl(idx4[jb], k + 12 + grp);
            RowVec<F8IN> v1 = ldrow<F8IN>(Sin, s1, q);
            RowVec<F8IN> v2 = ldrow<F8IN>(Sin, s2, q);
            RowVec<F8IN> v3 = ldrow<F8IN>(Sin, s3, q);
            RowVec<F8IN> v4 = ldrow<F8IN>(Sin, s4, q);
            acc8<F8IN>(accb, v1); acc8<F8IN>(accb, v2);
            acc8<F8IN>(accb, v3); acc8<F8IN>(accb, v4);
        }
        // cross-group butterfly reduce (4 groups -> full row sums)
#pragma unroll
        for (int r = 0; r < 8; ++r) {
            acca[r] += __shfl_xor(acca[r], 16);
            acca[r] += __shfl_xor(acca[r], 32);
            accb[r] += __shfl_xor(accb[r], 16);
            accb[r] += __shfl_xor(accb[r], 32);
        }
        if (grp == 0) {
            int ia = base + ja, ib = base + jb;
            float da = (ia < n) ? dis[ia] : 0.f;
            float db = (ib < n) ? dis[ib] : 0.f;
            plds4[(wave * 4 + ja) * 17 + q] =
                make_uint4(f2h2(da * acca[0], da * acca[1]),
                           f2h2(da * acca[2], da * acca[3]),
                           f2h2(da * acca[4], da * acca[5]),
                           f2h2(da * acca[6], da * acca[7]));
            plds4[(wave * 4 + jb) * 17 + q] =
                make_uint4(f2h2(db * accb[0], db * accb[1]),
                           f2h2(db * accb[2], db * accb[3]),
                           f2h2(db * accb[4], db * accb[5]),
                           f2h2(db * accb[6], db * accb[7]));
        }
    }
    __syncthreads();

    // ---- phase B: 16x128 GEMM out = [dis*] relu(P @ W + b) ----
    // wave w owns cols [w*32, w*32+32); 16 rows; 8 MFMA per wave.
    const int l16 = lane & 15, quad = lane >> 4;
    f32x4 acc2[2] = {};
#pragma unroll
    for (int kc = 0; kc < 4; ++kc) {
        int ko = kc * 32 + quad * 8;
        short8 a0 = *(const short8*)&plds4[(size_t)l16 * 17 + kc * 4 + quad];
#pragma unroll
        for (int ct = 0; ct < 2; ++ct) {
            short8 wh = *(const short8*)(WT + (size_t)(wave * 32 + ct * 16 + l16) * HID + ko);
            acc2[ct] = __builtin_amdgcn_mfma_f32_16x16x32_f16(wh, a0, acc2[ct], 0, 0, 0);
        }
    }
    ushort* so = (ushort*)Sout;
    int node = blk0 + l16;
    if (node < n) {
        float sc = scaleOut ? dis[node] : 1.f;
#pragma unroll
        for (int ct = 0; ct < 2; ++ct) {
            int cb = wave * 32 + ct * 16 + quad * 4;
            float4 bv = *(const float4*)(bias + cb);
            float o0 = fmaxf(acc2[ct][0] + bv.x, 0.f) * sc;
            float o1 = fmaxf(acc2[ct][1] + bv.y, 0.f) * sc;
            float o2 = fmaxf(acc2[ct][2] + bv.z, 0.f) * sc;
            float o3 = fmaxf(acc2[ct][3] + bv.w, 0.f) * sc;
            *(uint2*)(so + (size_t)node * HID + cb) = make_uint2(f2h2(o0, o1), f2h2(o2, o3));
        }
    }
}

// ---------------------------------------------------------------------------
// pool_partial (R13-proven): 8 row-chunks per graph -> 512 blocks; LDS
// cross-wave reduce; one fp32 atomicAdd per column into pooled[g][128].
// ---------------------------------------------------------------------------
__global__ __launch_bounds__(256) void pool_partial(
    const uint32* __restrict__ h, const int* __restrict__ gstart,
    float* __restrict__ pooled, int n) {
    __shared__ float red[4][128];
    const int g = blockIdx.x >> 3;
    const int c = blockIdx.x & 7;
    const int t = threadIdx.x;
    const int sub = t >> 6, cc = t & 63;

    const int start = gstart[g], end = gstart[g + 1];
    const int len = end - start;
    const int s0 = start + (int)(((long)len * c) >> 3);
    const int s1 = start + (int)(((long)len * (c + 1)) >> 3);

    float sx = 0.f, sy = 0.f;
    int i = s0 + sub;
    for (; i + 12 < s1; i += 16) {        // 4 rows x unroll 4 in flight
        uint32 u0 = h[(size_t)i * 64 + cc];
        uint32 u1 = h[(size_t)(i + 4) * 64 + cc];
        uint32 u2 = h[(size_t)(i + 8) * 64 + cc];
        uint32 u3 = h[(size_t)(i + 12) * 64 + cc];
        float2 v0 = h2f2(u0), v1 = h2f2(u1), v2 = h2f2(u2), v3 = h2f2(u3);
        sx += v0.x + v1.x + v2.x + v3.x;
        sy += v0.y + v1.y + v2.y + v3.y;
    }
    for (; i < s1; i += 4) {
        float2 v = h2f2(h[(size_t)i * 64 + cc]);
        sx += v.x; sy += v.y;
    }
    *(float2*)&red[sub][2 * cc] = make_float2(sx, sy);
    __syncthreads();

    if (t < 128) {
        float v = red[0][t] + red[1][t] + red[2][t] + red[3][t];
        atomicAdd(&pooled[g * HID + t], v);
    }
}

// ---------------------------------------------------------------------------
// MLP head: 64 blocks x 64 threads; mean from gstart counts.
// ---------------------------------------------------------------------------
__global__ void mlp_head(const float* __restrict__ pooled, const int* __restrict__ gstart,
                         const float* __restrict__ fc1w, const float* __restrict__ fc1b,
                         const float* __restrict__ fc2w, const float* __restrict__ fc2b,
                         float* __restrict__ out) {
    int g = blockIdx.x;
    int j = threadIdx.x;
    float inv = 1.0f / fmaxf((float)(gstart[g + 1] - gstart[g]), 1.0f);
    float z = fc1b[j];
#pragma unroll 8
    for (int k = 0; k < HID; ++k) z += (pooled[g * HID + k] * inv) * fc1w[k * 64 + j];
    z = fmaxf(z, 0.f);
    float v = z * fc2w[j];
#pragma unroll
    for (int off = 32; off > 0; off >>= 1) v += __shfl_down(v, off);
    if (j == 0) out[g] = v + fc2b[0];
}

// ---------------------------------------------------------------------------
extern "C" void kernel_launch(void* const* d_in, const int* in_sizes, int n_in,
                              void* d_out, int out_size, void* d_ws, size_t ws_size,
                              hipStream_t stream) {
    const float* x     = (const float*)d_in[0];
    const int*   ei    = (const int*)d_in[1];
    const int*   batch = (const int*)d_in[2];
    const float* W1    = (const float*)d_in[3];
    const float* b1    = (const float*)d_in[4];
    const float* W2    = (const float*)d_in[5];
    const float* b2    = (const float*)d_in[6];
    const float* W3    = (const float*)d_in[7];
    const float* b3    = (const float*)d_in[8];
    const float* fc1w  = (const float*)d_in[9];
    const float* fc1b  = (const float*)d_in[10];
    const float* fc2w  = (const float*)d_in[11];
    const float* fc2b  = (const float*)d_in[12];
    float* out = (float*)d_out;

    const int N = in_sizes[0] / 6;   // 50000
    const int E = in_sizes[1] / 2;   // 600000
    const int* src = ei;
    const int* dst = ei + E;

    char* ws = (char*)d_ws;
    char* p = ws;
    uint32* S1   = (uint32*)p;   p += (size_t)(N + 1) * 128;      // fp8 dis*h1 plane (+pad row)
    uint32* S2   = (uint32*)p;   p += (size_t)(N + 1) * 256;      // fp16 dis*h2 plane (+pad row)
    uint32* B1h  = (uint32*)p;   p += (size_t)N * 256;            // fp16 final acts (h3)
    float4* xp4  = (float4*)p;   p += (size_t)N * 32;             // dis-scaled x rows
    ushort* WT   = (ushort*)p;   p += 2 * 32768;                  // packed W2,W3 (fp16)
    float* dis     = (float*)p;  p += (size_t)N * 4;
    int*   fill    = (int*)p;    p += (size_t)N * 4;
    int*   csr     = (int*)p;    p += (size_t)N * CAP * 4;        // capacity CSR
    int*   gstart  = (int*)p;    p += (NGRAPH + 1) * 4;           // pool segment bounds
    float* pooled  = (float*)p;  p += NGRAPH * HID * 4;           // fp32 pool accum

    const int B = 256;
    const int EB = (E + B - 1) / B;

    // ---- setup + capacity-CSR build (no count pass, no scan) ----
    setup<<<(N + B - 1) / B, B, 0, stream>>>(fill, S1, S2, batch, gstart, pooled, N);
    csr_fill_pack<<<EB + 128, B, 0, stream>>>(src, dst, fill, csr, E, EB, W2, W3, WT);
    finalize<<<(N + B - 1) / B, B, 0, stream>>>(fill, dis, x, xp4, N);

    int l1Blocks = (int)(((size_t)N * 16 + B - 1) / B);    // 4 nodes/wave
    int fusedBlocks = (N + NPB - 1) / NPB;

    // ---- layer 1 (4 nodes/wave) -> S1 fp8 ----
    layer1_quad<<<l1Blocks, B, 0, stream>>>(xp4, fill, csr, dis, W1, b1, S1, N);

    // ---- layer 2: fp8-in gather (A of the line-count A/B) -> S2 fp16 ----
    layer_agg_gemm<6, true><<<fusedBlocks, B, 0, stream>>>(S1, fill, csr, dis, WT, b2, S2, N, 1);

    // ---- layer 3: fp16-in gather (B reference) -> B1h ----
    layer_agg_gemm<5, false><<<fusedBlocks, B, 0, stream>>>(S2, fill, csr, dis, WT + 16384, b3, B1h, N, 0);

    // ---- pool: 512 blocks (8 chunks/graph) -> fp32 atomics ----
    pool_partial<<<NGRAPH * 8, B, 0, stream>>>(B1h, gstart, pooled, N);

    // ---- head ----
    mlp_head<<<NGRAPH, 64, 0, stream>>>(pooled, gstart, fc1w, fc1b, fc2w, fc2b, out);
}

// Round 16
// 205.483 us; speedup vs baseline: 1.2108x; 1.0327x over previous
//
#include <hip/hip_runtime.h>
#include <hip/hip_fp16.h>

#define HID 128
#define NGRAPH 64
#define CAP 64        // fixed CSR capacity per row (Poisson lambda=12 -> safe)
#define NPB 16        // nodes per block (4 waves x 4 nodes) in fused layers

typedef unsigned int uint32;
typedef unsigned short ushort;
using short8 = __attribute__((ext_vector_type(8))) short;
using f32x4  = __attribute__((ext_vector_type(4))) float;

// fp16 pack/unpack helpers (RNE via v_cvt)
__device__ __forceinline__ float2 h2f2(uint32 u) {
    __half2 h = *(__half2*)&u;
    return __half22float2(h);
}
__device__ __forceinline__ uint32 f2h2(float a, float b) {
    __half2 h;
    h.x = __float2half(a);
    h.y = __float2half(b);
    return *(uint32*)&h;
}

// unpack one fp16x8 row chunk and accumulate into 8 fp32 lane-cols
__device__ __forceinline__ void accum4(float* acc, uint4 v) {
    float2 e0 = h2f2(v.x), e1 = h2f2(v.y), e2 = h2f2(v.z), e3 = h2f2(v.w);
    acc[0] += e0.x; acc[1] += e0.y; acc[2] += e1.x; acc[3] += e1.y;
    acc[4] += e2.x; acc[5] += e2.y; acc[6] += e3.x; acc[7] += e3.y;
}

// ---- gather-row abstraction: fp16 (uint4, 256B rows) vs fp8 (uint2, 128B) --
template<bool F8> struct RowVec;
template<> struct RowVec<false> { uint4 v; };
template<> struct RowVec<true>  { uint2 v; };

template<bool F8>
__device__ __forceinline__ RowVec<F8> ldrow(const uint32* __restrict__ S, int s, int q) {
    RowVec<F8> r;
    if constexpr (F8) r.v = *(const uint2*)(S + (size_t)s * 32 + q * 2);
    else              r.v = *(const uint4*)(S + (size_t)s * 64 + q * 4);
    return r;
}
template<bool F8>
__device__ __forceinline__ void acc8(float* a, RowVec<F8> r) {
    if constexpr (F8) {
        auto e0 = __builtin_amdgcn_cvt_pk_f32_fp8(r.v.x, false);
        auto e1 = __builtin_amdgcn_cvt_pk_f32_fp8(r.v.x, true);
        auto e2 = __builtin_amdgcn_cvt_pk_f32_fp8(r.v.y, false);
        auto e3 = __builtin_amdgcn_cvt_pk_f32_fp8(r.v.y, true);
        a[0] += e0[0]; a[1] += e0[1]; a[2] += e1[0]; a[3] += e1[1];
        a[4] += e2[0]; a[5] += e2[1]; a[6] += e3[0]; a[7] += e3[1];
    } else {
        accum4(a, r.v);
    }
}

// ---------------------------------------------------------------------------
// setup: fill=0, zero pad rows (S1 fp8: 32 u32; S2 fp16: 64 u32), zero
// pooled, and build gstart[0..NGRAPH] from sorted batch.
// ---------------------------------------------------------------------------
__global__ void setup(int* __restrict__ fill, uint32* __restrict__ s1,
                      uint32* __restrict__ s2, const int* __restrict__ batch,
                      int* __restrict__ gstart, float* __restrict__ pooled, int n) {
    int i = blockIdx.x * blockDim.x + threadIdx.x;
    if (i < n) fill[i] = 0;
    if (i < 32) s1[(size_t)n * 32 + i] = 0u;   // fp8 pad row (128 B)
    if (i < 64) s2[(size_t)n * 64 + i] = 0u;   // fp16 pad row (256 B)
    if (i < NGRAPH * HID) pooled[i] = 0.f;
    if (i < n) {
        int b0 = batch[i];
        if (i == 0) {
            for (int g = 0; g <= b0; ++g) gstart[g] = 0;   // leading (possibly empty)
        }
        if (i + 1 < n) {
            int b1 = batch[i + 1];
            for (int g = b0 + 1; g <= b1; ++g) gstart[g] = i + 1;
        } else {
            for (int g = b0 + 1; g <= NGRAPH; ++g) gstart[g] = n;  // trailing
        }
    }
}

// ---------------------------------------------------------------------------
// capacity-CSR fill + weight pack fused (single atomic pass, no scan).
// R16: PLAIN store for the CSR scatter. R13's NT store was wrong here:
// consecutive pos for one node share a 64B line, so L2 coalesces plain
// stores to ~1 line/node writeback; NT pushed each 4B store to DRAM at
// random-write BW (R14 counters: 36.9 MB WRITE_SIZE, 45.9 us, 0.4% VALU).
// Mechanism check this round: WRITE_SIZE < 8 MB, dur ~28-35 us.
// NOTE: int (not ushort) CSR deliberately — ushort variant core-dumped on HW.
// ---------------------------------------------------------------------------
__global__ void csr_fill_pack(const int* __restrict__ src, const int* __restrict__ dst,
                              int* __restrict__ fill, int* __restrict__ csr,
                              int E, int EB,
                              const float* __restrict__ W2, const float* __restrict__ W3,
                              ushort* __restrict__ wt) {
    int b = blockIdx.x;
    if (b < EB) {
        int e = b * blockDim.x + threadIdx.x;
        if (e >= E) return;
        int d = dst[e];
        int pos = atomicAdd(&fill[d], 1);
        if (pos < CAP) csr[(size_t)d * CAP + pos] = src[e];
    } else {
        int t = (b - EB) * blockDim.x + threadIdx.x;   // 0..32767
        int sel = t >> 14;                             // 0: W2, 1: W3
        int idx = t & 16383;
        int nn = idx >> 7, kk = idx & 127;
        const float* W = sel ? W3 : W2;
        wt[sel * 16384 + idx] = __half_as_ushort(__float2half(W[kk * HID + nn]));
    }
}

// ---------------------------------------------------------------------------
// finalize: dis = 1/sqrt(deg) with deg = fill+1 (self-loop); pack
// xp[i] = dis[i] * x[i,:] into 32 B rows (vector-gatherable by layer 1).
// ---------------------------------------------------------------------------
__global__ void finalize(const int* __restrict__ fill, float* __restrict__ dis,
                         const float* __restrict__ x, float4* __restrict__ xp4, int n) {
    int i = blockIdx.x * blockDim.x + threadIdx.x;
    if (i >= n) return;
    int d = fill[i] + 1;
    float di = (float)(1.0 / sqrt((double)d));
    dis[i] = di;
    const float* xi = x + (size_t)i * 6;
    xp4[(size_t)i * 2]     = make_float4(di * xi[0], di * xi[1], di * xi[2], di * xi[3]);
    xp4[(size_t)i * 2 + 1] = make_float4(di * xi[4], di * xi[5], 0.f, 0.f);
}

// ---------------------------------------------------------------------------
// layer 1 (R12-proven structure): FOUR nodes per wave (16-lane group/node).
// Output plane S1 is fp8 e4m3 (128 B rows) via HW cvt_pk_fp8 (RNE).
// PRECISION BUDGET (R14/R15 measured): ONE fp8 plane -> absmax 1.53e-5,
// passes (threshold 1.98e-5). TWO fp8 planes -> 3.43e-5, FAILS. S2 must
// remain fp16. Do not re-attempt fp8 S2.
// ---------------------------------------------------------------------------
__global__ __launch_bounds__(256) void layer1_quad(
    const float4* __restrict__ xp4, const int* __restrict__ fill,
    const int* __restrict__ csr, const float* __restrict__ dis,
    const float* __restrict__ W1, const float* __restrict__ b1,
    uint32* __restrict__ S1, int n) {
    int t = blockIdx.x * blockDim.x + threadIdx.x;
    int wv = t >> 6;                 // wave id
    int lane = t & 63;
    int sub = lane >> 4;             // node slot within wave (0..3)
    int sl  = lane & 15;             // lane slot within node
    int i = wv * 4 + sub;
    if (i >= n) return;              // whole 16-lane group exits together

    int m = fill[i]; if (m > CAP) m = CAP;
    float a0 = 0.f, a1 = 0.f, a2 = 0.f, a3 = 0.f, a4 = 0.f, a5 = 0.f;
#pragma unroll
    for (int r = 0; r < 4; ++r) {
        int slot = sl + 16 * r;
        if (slot < m) {
            int s = csr[(size_t)i * CAP + slot];
            float4 p0 = xp4[(size_t)s * 2];
            float4 p1 = xp4[(size_t)s * 2 + 1];
            a0 += p0.x; a1 += p0.y; a2 += p0.z;
            a3 += p0.w; a4 += p1.x; a5 += p1.y;
        }
    }
    // butterfly reduce within the 16-lane group (offsets stay in-group)
#pragma unroll
    for (int off = 8; off > 0; off >>= 1) {
        a0 += __shfl_xor(a0, off); a1 += __shfl_xor(a1, off);
        a2 += __shfl_xor(a2, off); a3 += __shfl_xor(a3, off);
        a4 += __shfl_xor(a4, off); a5 += __shfl_xor(a5, off);
    }
    float di = dis[i];
    float4 s0 = xp4[(size_t)i * 2];
    float4 s1v = xp4[(size_t)i * 2 + 1];
    float xa[6];
    xa[0] = di * (s0.x + a0); xa[1] = di * (s0.y + a1);
    xa[2] = di * (s0.z + a2); xa[3] = di * (s0.w + a3);
    xa[4] = di * (s1v.x + a4); xa[5] = di * (s1v.y + a5);

    int c0 = sl * 8;                 // this lane's 8 output cols
    float z[8];
#pragma unroll
    for (int j = 0; j < 8; ++j) z[j] = b1[c0 + j];
#pragma unroll
    for (int k = 0; k < 6; ++k) {
#pragma unroll
        for (int j = 0; j < 8; ++j) z[j] += xa[k] * W1[k * HID + c0 + j];
    }
    float o[8];
#pragma unroll
    for (int j = 0; j < 8; ++j) o[j] = di * fmaxf(z[j], 0.f);
    uint32 r0 = 0, r1 = 0;
    r0 = __builtin_amdgcn_cvt_pk_fp8_f32(o[0], o[1], r0, false);
    r0 = __builtin_amdgcn_cvt_pk_fp8_f32(o[2], o[3], r0, true);
    r1 = __builtin_amdgcn_cvt_pk_fp8_f32(o[4], o[5], r1, false);
    r1 = __builtin_amdgcn_cvt_pk_fp8_f32(o[6], o[7], r1, true);
    *(uint2*)(S1 + (size_t)i * 32 + sl * 2) = make_uint2(r0, r1);
}

// ---------------------------------------------------------------------------
// FUSED GCN layer: aggregate-then-GEMM. R10-proven structure (16 nodes/blk,
// 4/wave, 2-pair body, 8 row-loads in flight). F8IN: fp8 e4m3 128 B input
// rows (halves random gather line count — R14 verified −7 us/layer).
// ILP-deepening past 8 is source-unreachable (R8/R9/R11). Do not revisit.
// ---------------------------------------------------------------------------
template<int MINW, bool F8IN>
__global__ __launch_bounds__(256, MINW) void layer_agg_gemm(
    const uint32* __restrict__ Sin, const int* __restrict__ fill,
    const int* __restrict__ csr, const float* __restrict__ dis,
    const ushort* __restrict__ WT, const float* __restrict__ bias,
    uint32* __restrict__ Sout, int n, int scaleOut) {
    __shared__ uint4 plds4[NPB * 17];           // 16 rows x 272 B = 4352 B
    const int wave = threadIdx.x >> 6;
    const int lane = threadIdx.x & 63;
    const int grp = lane >> 4;                  // edge-slot group 0..3
    const int q   = lane & 15;                  // col chunk (8 values)
    const int blk0 = blockIdx.x * NPB;
    const int base = blk0 + wave * 4;

    // ---- prologue: prefetch fill + csr index vectors for the 4 nodes ----
    int mt4[4];    // edge count incl. appended self-loop (<= 64)
    int idx4[4];   // this lane's edge slot for node j (pad -> zero row n)
#pragma unroll
    for (int j = 0; j < 4; ++j) {
        int i = base + j;
        int fv = (i < n) ? fill[i] : 0;
        int m = fv > CAP ? CAP : fv;
        idx4[j] = (lane < m) ? csr[(size_t)i * CAP + lane]
                             : ((lane == m && i < n && m < CAP) ? i : n);
        mt4[j] = m + (m < CAP ? 1 : 0);   // append self as slot m
    }

    // ---- phase A: paired gather-aggregate into LDS (2 pairs) ----
#pragma unroll
    for (int jp = 0; jp < 2; ++jp) {
        const int ja = jp * 2, jb = ja + 1;
        float acca[8] = {0.f, 0.f, 0.f, 0.f, 0.f, 0.f, 0.f, 0.f};
        float accb[8] = {0.f, 0.f, 0.f, 0.f, 0.f, 0.f, 0.f, 0.f};
        // first 16-edge round of BOTH nodes co-issued (8 row-loads in flight)
        {
            int sa1 = __shfl(idx4[ja], grp);
            int sa2 = __shfl(idx4[ja], 4 + grp);
            int sa3 = __shfl(idx4[ja], 8 + grp);
            int sa4 = __shfl(idx4[ja], 12 + grp);
            int sb1 = __shfl(idx4[jb], grp);
            int sb2 = __shfl(idx4[jb], 4 + grp);
            int sb3 = __shfl(idx4[jb], 8 + grp);
            int sb4 = __shfl(idx4[jb], 12 + grp);
            RowVec<F8IN> va1 = ldrow<F8IN>(Sin, sa1, q);
            RowVec<F8IN> va2 = ldrow<F8IN>(Sin, sa2, q);
            RowVec<F8IN> va3 = ldrow<F8IN>(Sin, sa3, q);
            RowVec<F8IN> va4 = ldrow<F8IN>(Sin, sa4, q);
            RowVec<F8IN> vb1 = ldrow<F8IN>(Sin, sb1, q);
            RowVec<F8IN> vb2 = ldrow<F8IN>(Sin, sb2, q);
            RowVec<F8IN> vb3 = ldrow<F8IN>(Sin, sb3, q);
            RowVec<F8IN> vb4 = ldrow<F8IN>(Sin, sb4, q);
            acc8<F8IN>(acca, va1); acc8<F8IN>(acca, va2);
            acc8<F8IN>(acca, va3); acc8<F8IN>(acca, va4);
            acc8<F8IN>(accb, vb1); acc8<F8IN>(accb, vb2);
            acc8<F8IN>(accb, vb3); acc8<F8IN>(accb, vb4);
        }
        // remainder rounds (m >= 16), serial per node
        for (int k = 16; k < mt4[ja]; k += 16) {
            int s1 = __shfl(idx4[ja], k + grp);
            int s2 = __shfl(idx4[ja], k + 4 + grp);
            int s3 = __shfl(idx4[ja], k + 8 + grp);
            int s4 = __shfl(idx4[ja], k + 12 + grp);
            RowVec<F8IN> v1 = ldrow<F8IN>(Sin, s1, q);
            RowVec<F8IN> v2 = ldrow<F8IN>(Sin, s2, q);
            RowVec<F8IN> v3 = ldrow<F8IN>(Sin, s3, q);
            RowVec<F8IN> v4 = ldrow<F8IN>(Sin, s4, q);
            acc8<F8IN>(acca, v1); acc8<F8IN>(acca, v2);
            acc8<F8IN>(acca, v3); acc8<F8IN>(acca, v4);
        }
        for (int k = 16; k < mt4[jb]; k += 16) {
            int s1 = __shfl(idx4[jb], k + grp);
            int s2 = __shfl(idx4[jb], k + 4 + grp);
            int s3 = __shfl(idx4[jb], k + 8 + grp);
            int s4 = __shfl(idx4[jb], k + 12 + grp);
            RowVec<F8IN> v1 = ldrow<F8IN>(Sin, s1, q);
            RowVec<F8IN> v2 = ldrow<F8IN>(Sin, s2, q);
            RowVec<F8IN> v3 = ldrow<F8IN>(Sin, s3, q);
            RowVec<F8IN> v4 = ldrow<F8IN>(Sin, s4, q);
            acc8<F8IN>(accb, v1); acc8<F8IN>(accb, v2);
            acc8<F8IN>(accb, v3); acc8<F8IN>(accb, v4);
        }
        // cross-group butterfly reduce (4 groups -> full row sums)
#pragma unroll
        for (int r = 0; r < 8; ++r) {
            acca[r] += __shfl_xor(acca[r], 16);
            acca[r] += __shfl_xor(acca[r], 32);
            accb[r] += __shfl_xor(accb[r], 16);
            accb[r] += __shfl_xor(accb[r], 32);
        }
        if (grp == 0) {
            int ia = base + ja, ib = base + jb;
            float da = (ia < n) ? dis[ia] : 0.f;
            float db = (ib < n) ? dis[ib] : 0.f;
            plds4[(wave * 4 + ja) * 17 + q] =
                make_uint4(f2h2(da * acca[0], da * acca[1]),
                           f2h2(da * acca[2], da * acca[3]),
                           f2h2(da * acca[4], da * acca[5]),
                           f2h2(da * acca[6], da * acca[7]));
            plds4[(wave * 4 + jb) * 17 + q] =
                make_uint4(f2h2(db * accb[0], db * accb[1]),
                           f2h2(db * accb[2], db * accb[3]),
                           f2h2(db * accb[4], db * accb[5]),
                           f2h2(db * accb[6], db * accb[7]));
        }
    }
    __syncthreads();

    // ---- phase B: 16x128 GEMM out = [dis*] relu(P @ W + b) ----
    // wave w owns cols [w*32, w*32+32); 16 rows; 8 MFMA per wave.
    const int l16 = lane & 15, quad = lane >> 4;
    f32x4 acc2[2] = {};
#pragma unroll
    for (int kc = 0; kc < 4; ++kc) {
        int ko = kc * 32 + quad * 8;
        short8 a0 = *(const short8*)&plds4[(size_t)l16 * 17 + kc * 4 + quad];
#pragma unroll
        for (int ct = 0; ct < 2; ++ct) {
            short8 wh = *(const short8*)(WT + (size_t)(wave * 32 + ct * 16 + l16) * HID + ko);
            acc2[ct] = __builtin_amdgcn_mfma_f32_16x16x32_f16(wh, a0, acc2[ct], 0, 0, 0);
        }
    }
    ushort* so = (ushort*)Sout;
    int node = blk0 + l16;
    if (node < n) {
        float sc = scaleOut ? dis[node] : 1.f;
#pragma unroll
        for (int ct = 0; ct < 2; ++ct) {
            int cb = wave * 32 + ct * 16 + quad * 4;
            float4 bv = *(const float4*)(bias + cb);
            float o0 = fmaxf(acc2[ct][0] + bv.x, 0.f) * sc;
            float o1 = fmaxf(acc2[ct][1] + bv.y, 0.f) * sc;
            float o2 = fmaxf(acc2[ct][2] + bv.z, 0.f) * sc;
            float o3 = fmaxf(acc2[ct][3] + bv.w, 0.f) * sc;
            *(uint2*)(so + (size_t)node * HID + cb) = make_uint2(f2h2(o0, o1), f2h2(o2, o3));
        }
    }
}

// ---------------------------------------------------------------------------
// pool_partial (R13-proven): 8 row-chunks per graph -> 512 blocks; LDS
// cross-wave reduce; one fp32 atomicAdd per column into pooled[g][128].
// ---------------------------------------------------------------------------
__global__ __launch_bounds__(256) void pool_partial(
    const uint32* __restrict__ h, const int* __restrict__ gstart,
    float* __restrict__ pooled, int n) {
    __shared__ float red[4][128];
    const int g = blockIdx.x >> 3;
    const int c = blockIdx.x & 7;
    const int t = threadIdx.x;
    const int sub = t >> 6, cc = t & 63;

    const int start = gstart[g], end = gstart[g + 1];
    const int len = end - start;
    const int s0 = start + (int)(((long)len * c) >> 3);
    const int s1 = start + (int)(((long)len * (c + 1)) >> 3);

    float sx = 0.f, sy = 0.f;
    int i = s0 + sub;
    for (; i + 12 < s1; i += 16) {        // 4 rows x unroll 4 in flight
        uint32 u0 = h[(size_t)i * 64 + cc];
        uint32 u1 = h[(size_t)(i + 4) * 64 + cc];
        uint32 u2 = h[(size_t)(i + 8) * 64 + cc];
        uint32 u3 = h[(size_t)(i + 12) * 64 + cc];
        float2 v0 = h2f2(u0), v1 = h2f2(u1), v2 = h2f2(u2), v3 = h2f2(u3);
        sx += v0.x + v1.x + v2.x + v3.x;
        sy += v0.y + v1.y + v2.y + v3.y;
    }
    for (; i < s1; i += 4) {
        float2 v = h2f2(h[(size_t)i * 64 + cc]);
        sx += v.x; sy += v.y;
    }
    *(float2*)&red[sub][2 * cc] = make_float2(sx, sy);
    __syncthreads();

    if (t < 128) {
        float v = red[0][t] + red[1][t] + red[2][t] + red[3][t];
        atomicAdd(&pooled[g * HID + t], v);
    }
}

// ---------------------------------------------------------------------------
// MLP head: 64 blocks x 64 threads; mean from gstart counts.
// ---------------------------------------------------------------------------
__global__ void mlp_head(const float* __restrict__ pooled, const int* __restrict__ gstart,
                         const float* __restrict__ fc1w, const float* __restrict__ fc1b,
                         const float* __restrict__ fc2w, const float* __restrict__ fc2b,
                         float* __restrict__ out) {
    int g = blockIdx.x;
    int j = threadIdx.x;
    float inv = 1.0f / fmaxf((float)(gstart[g + 1] - gstart[g]), 1.0f);
    float z = fc1b[j];
#pragma unroll 8
    for (int k = 0; k < HID; ++k) z += (pooled[g * HID + k] * inv) * fc1w[k * 64 + j];
    z = fmaxf(z, 0.f);
    float v = z * fc2w[j];
#pragma unroll
    for (int off = 32; off > 0; off >>= 1) v += __shfl_down(v, off);
    if (j == 0) out[g] = v + fc2b[0];
}

// ---------------------------------------------------------------------------
extern "C" void kernel_launch(void* const* d_in, const int* in_sizes, int n_in,
                              void* d_out, int out_size, void* d_ws, size_t ws_size,
                              hipStream_t stream) {
    const float* x     = (const float*)d_in[0];
    const int*   ei    = (const int*)d_in[1];
    const int*   batch = (const int*)d_in[2];
    const float* W1    = (const float*)d_in[3];
    const float* b1    = (const float*)d_in[4];
    const float* W2    = (const float*)d_in[5];
    const float* b2    = (const float*)d_in[6];
    const float* W3    = (const float*)d_in[7];
    const float* b3    = (const float*)d_in[8];
    const float* fc1w  = (const float*)d_in[9];
    const float* fc1b  = (const float*)d_in[10];
    const float* fc2w  = (const float*)d_in[11];
    const float* fc2b  = (const float*)d_in[12];
    float* out = (float*)d_out;

    const int N = in_sizes[0] / 6;   // 50000
    const int E = in_sizes[1] / 2;   // 600000
    const int* src = ei;
    const int* dst = ei + E;

    char* ws = (char*)d_ws;
    char* p = ws;
    uint32* S1   = (uint32*)p;   p += (size_t)(N + 1) * 128;      // fp8 dis*h1 plane (+pad row)
    uint32* S2   = (uint32*)p;   p += (size_t)(N + 1) * 256;      // fp16 dis*h2 plane (+pad row)
    uint32* B1h  = (uint32*)p;   p += (size_t)N * 256;            // fp16 final acts (h3)
    float4* xp4  = (float4*)p;   p += (size_t)N * 32;             // dis-scaled x rows
    ushort* WT   = (ushort*)p;   p += 2 * 32768;                  // packed W2,W3 (fp16)
    float* dis     = (float*)p;  p += (size_t)N * 4;
    int*   fill    = (int*)p;    p += (size_t)N * 4;
    int*   csr     = (int*)p;    p += (size_t)N * CAP * 4;        // capacity CSR
    int*   gstart  = (int*)p;    p += (NGRAPH + 1) * 4;           // pool segment bounds
    float* pooled  = (float*)p;  p += NGRAPH * HID * 4;           // fp32 pool accum

    const int B = 256;
    const int EB = (E + B - 1) / B;

    // ---- setup + capacity-CSR build (no count pass, no scan) ----
    setup<<<(N + B - 1) / B, B, 0, stream>>>(fill, S1, S2, batch, gstart, pooled, N);
    csr_fill_pack<<<EB + 128, B, 0, stream>>>(src, dst, fill, csr, E, EB, W2, W3, WT);
    finalize<<<(N + B - 1) / B, B, 0, stream>>>(fill, dis, x, xp4, N);

    int l1Blocks = (int)(((size_t)N * 16 + B - 1) / B);    // 4 nodes/wave
    int fusedBlocks = (N + NPB - 1) / NPB;

    // ---- layer 1 (4 nodes/wave) -> S1 fp8 ----
    layer1_quad<<<l1Blocks, B, 0, stream>>>(xp4, fill, csr, dis, W1, b1, S1, N);

    // ---- layer 2: fp8-in gather -> S2 fp16 ----
    layer_agg_gemm<6, true><<<fusedBlocks, B, 0, stream>>>(S1, fill, csr, dis, WT, b2, S2, N, 1);

    // ---- layer 3: fp16-in gather -> B1h fp16 ----
    layer_agg_gemm<5, false><<<fusedBlocks, B, 0, stream>>>(S2, fill, csr, dis, WT + 16384, b3, B1h, N, 0);

    // ---- pool: 512 blocks (8 chunks/graph) -> fp32 atomics ----
    pool_partial<<<NGRAPH * 8, B, 0, stream>>>(B1h, gstart, pooled, N);

    // ---- head ----
    mlp_head<<<NGRAPH, 64, 0, stream>>>(pooled, gstart, fc1w, fc1b, fc2w, fc2b, out);
}